// Round 1
// baseline (2310.772 us; speedup 1.0000x reference)
//
#include <hip/hip_runtime.h>
#include <hip/hip_bf16.h>

#define AS1 __attribute__((address_space(1)))
#define AS3 __attribute__((address_space(3)))

typedef __attribute__((ext_vector_type(8))) short short8;
typedef __attribute__((ext_vector_type(4))) float f32x4;

constexpr int BB = 4, TT = 768, DDIM = 512, LL = 6, VV = 50304, FF = 2048;
constexpr int MM = BB * TT;  // 3072 rows of the activation matrix

// ---------- helpers ----------
__device__ inline unsigned short f2b(float f) {
  union { float f; unsigned u; } a; a.f = f;
  unsigned u = a.u;
  return (unsigned short)((u + 0x7FFFu + ((u >> 16) & 1u)) >> 16);  // RNE
}
__device__ inline float b2f(unsigned short u) {
  union { unsigned u; float f; } a; a.u = ((unsigned)u) << 16; return a.f;
}

// ---------- f32 -> bf16 convert ----------
__global__ void cvt_bf16(const float* __restrict__ in, ushort* __restrict__ out, int n) {
  size_t i = ((size_t)blockIdx.x * 256 + threadIdx.x) * 4;
  if (i >= (size_t)n) return;
  float4 v = *(const float4*)(in + i);
  ushort4 o = { f2b(v.x), f2b(v.y), f2b(v.z), f2b(v.w) };
  *(ushort4*)(out + i) = o;
}

// ---------- embedding: x = wte[idx] + wpe[t] ----------
__global__ void embed_kernel(const int* __restrict__ idx, const float* __restrict__ wte,
                             const float* __restrict__ wpe, float* __restrict__ x,
                             ushort* __restrict__ xb) {
  int row = blockIdx.x;          // 0..MM-1  (= b*T + t)
  int t = row % TT;
  int tok = idx[row];
  int c = threadIdx.x * 4;       // 128 threads * 4 = 512
  float4 a = *(const float4*)(wte + (size_t)tok * DDIM + c);
  float4 p = *(const float4*)(wpe + (size_t)t * DDIM + c);
  a.x += p.x; a.y += p.y; a.z += p.z; a.w += p.w;
  *(float4*)(x + (size_t)row * DDIM + c) = a;
  ushort4 o = { f2b(a.x), f2b(a.y), f2b(a.z), f2b(a.w) };
  *(ushort4*)(xb + (size_t)row * DDIM + c) = o;
}

// ---------- GEMM: C[M,N] = A[M,K](bf16) * Bw[N,K]^T(bf16) + bias ----------
// 128x128 tile, BK=32, 4 waves (2x2 of 64x64), 16x16x32 bf16 MFMA.
template <int RELU, int OUTBF16>
__global__ __launch_bounds__(256) void gemm_bt(
    const ushort* __restrict__ A, const ushort* __restrict__ Bw,
    const float* __restrict__ bias, void* __restrict__ Cv, int Ndim, int K) {
  __shared__ ushort sA[128 * 32];
  __shared__ ushort sB[128 * 32];
  const int tid = threadIdx.x;
  const int wid = tid >> 6, lane = tid & 63;
  const int m0 = blockIdx.y * 128, n0 = blockIdx.x * 128;
  const int wm = (wid >> 1) * 64, wn = (wid & 1) * 64;

  f32x4 zero = {0.f, 0.f, 0.f, 0.f};
  f32x4 acc[4][4];
#pragma unroll
  for (int i = 0; i < 4; i++)
#pragma unroll
    for (int j = 0; j < 4; j++) acc[i][j] = zero;

  const int r4 = tid >> 2;          // staging row (0..63 per round)
  const int c8 = (tid & 3) * 8;     // bf16 element offset (16B chunk)
  const ushort* gA = A + (size_t)(m0 + r4) * K + c8;
  const ushort* gB = Bw + (size_t)(n0 + r4) * K + c8;
  const size_t K64 = (size_t)64 * K;

  ushort* sAw = sA + wid * 512;     // wave-uniform LDS staging base
  ushort* sBw = sB + wid * 512;

  const int fr = lane & 15;
  const int fk = (lane >> 4) * 8;
  const ushort* pa0 = sA + (wm + fr) * 32 + fk;
  const ushort* pb0 = sB + (wn + fr) * 32 + fk;

  const int nK = K >> 5;
  for (int kk = 0; kk < nK; ++kk) {
    const ushort* a0 = gA + kk * 32;
    const ushort* b0 = gB + kk * 32;
    __builtin_amdgcn_global_load_lds((const AS1 void*)a0,         (AS3 void*)sAw,          16, 0, 0);
    __builtin_amdgcn_global_load_lds((const AS1 void*)(a0 + K64), (AS3 void*)(sAw + 2048), 16, 0, 0);
    __builtin_amdgcn_global_load_lds((const AS1 void*)b0,         (AS3 void*)sBw,          16, 0, 0);
    __builtin_amdgcn_global_load_lds((const AS1 void*)(b0 + K64), (AS3 void*)(sBw + 2048), 16, 0, 0);
    __syncthreads();
    short8 af[4], bf[4];
#pragma unroll
    for (int i = 0; i < 4; i++) {
      af[i] = *(const short8*)(pa0 + i * 16 * 32);
      bf[i] = *(const short8*)(pb0 + i * 16 * 32);
    }
#pragma unroll
    for (int i = 0; i < 4; i++)
#pragma unroll
      for (int j = 0; j < 4; j++)
        acc[i][j] = __builtin_amdgcn_mfma_f32_16x16x32_bf16(af[i], bf[j], acc[i][j], 0, 0, 0);
    __syncthreads();
  }

  // epilogue: C/D layout col=lane&15, row=(lane>>4)*4+reg  [guide §3, m89-verified]
  const int cr = (lane >> 4) * 4;
  const int cc = lane & 15;
#pragma unroll
  for (int j = 0; j < 4; j++) {
    const int gcol = n0 + wn + j * 16 + cc;
    const float bv = bias ? bias[gcol] : 0.0f;
#pragma unroll
    for (int i = 0; i < 4; i++) {
      const int grow = m0 + wm + i * 16 + cr;
#pragma unroll
      for (int rr = 0; rr < 4; ++rr) {
        float v = acc[i][j][rr] + bv;
        if (RELU) v = fmaxf(v, 0.0f);
        if (OUTBF16)
          ((ushort*)Cv)[(size_t)(grow + rr) * Ndim + gcol] = f2b(v);
        else
          ((float*)Cv)[(size_t)(grow + rr) * Ndim + gcol] = v;
      }
    }
  }
}

// ---------- fused causal attention (flash-style, f32 VALU) ----------
// grid: (T/64, B*8). One block = one (b, h, 64-row q-tile). 256 threads.
__global__ __launch_bounds__(256) void attn_fwd(const ushort* __restrict__ qkv,
                                                ushort* __restrict__ yb) {
  __shared__ float sQ[64 * 64];
  __shared__ float sK[64 * 64];
  __shared__ float sV[64 * 64];
  __shared__ float sP[64 * 64];
  const int tid = threadIdx.x;
  const int qt = blockIdx.x;
  const int b = blockIdx.y >> 3, h = blockIdx.y & 7;
  const int rr = tid >> 2;          // row 0..63 (4 lanes per row)
  const int c16 = (tid & 3) * 16;   // 16-wide column/j/dim slice
  const int q0 = qt * 64;

  {  // load Q tile -> LDS (f32)
    const ushort* qp = qkv + (size_t)(b * TT + q0 + rr) * 1536 + h * 64 + c16;
    short8 v0 = *(const short8*)qp;
    short8 v1 = *(const short8*)(qp + 8);
#pragma unroll
    for (int i = 0; i < 8; i++) {
      sQ[rr * 64 + c16 + i] = b2f((unsigned short)v0[i]);
      sQ[rr * 64 + c16 + 8 + i] = b2f((unsigned short)v1[i]);
    }
  }

  float mrow = -INFINITY, lrow = 0.0f;
  f32x4 zero = {0.f, 0.f, 0.f, 0.f};
  f32x4 acc4[4] = {zero, zero, zero, zero};

  for (int kt = 0; kt <= qt; ++kt) {
    __syncthreads();  // protect prior-tile sK/sV/sP readers (and Q store, tile 0)
    const int k0 = kt * 64;
    {  // load K,V tiles
      const ushort* kp = qkv + (size_t)(b * TT + k0 + rr) * 1536 + 512 + h * 64 + c16;
      short8 v0 = *(const short8*)kp;
      short8 v1 = *(const short8*)(kp + 8);
      const ushort* vp = kp + 512;
      short8 w0 = *(const short8*)vp;
      short8 w1 = *(const short8*)(vp + 8);
#pragma unroll
      for (int i = 0; i < 8; i++) {
        sK[rr * 64 + c16 + i] = b2f((unsigned short)v0[i]);
        sK[rr * 64 + c16 + 8 + i] = b2f((unsigned short)v1[i]);
        sV[rr * 64 + c16 + i] = b2f((unsigned short)w0[i]);
        sV[rr * 64 + c16 + 8 + i] = b2f((unsigned short)w1[i]);
      }
    }
    __syncthreads();

    // S = Q K^T / 8  (thread: row rr, 16 js at c16)
    float s[16];
    {
      const f32x4* qv = (const f32x4*)(sQ + rr * 64);
#pragma unroll
      for (int jj = 0; jj < 16; jj++) {
        const f32x4* kv = (const f32x4*)(sK + (c16 + jj) * 64);
        f32x4 sum4 = zero;
#pragma unroll
        for (int d4 = 0; d4 < 16; ++d4) sum4 += qv[d4] * kv[d4];
        float sum = (sum4[0] + sum4[1]) + (sum4[2] + sum4[3]);
        s[jj] = ((k0 + c16 + jj) <= (q0 + rr)) ? sum * 0.125f : -INFINITY;
      }
    }
    // online softmax (4-lane group per row)
    float tmax = s[0];
#pragma unroll
    for (int jj = 1; jj < 16; jj++) tmax = fmaxf(tmax, s[jj]);
    tmax = fmaxf(tmax, __shfl_xor(tmax, 1));
    tmax = fmaxf(tmax, __shfl_xor(tmax, 2));
    const float mnew = fmaxf(mrow, tmax);
    const float scale = __expf(mrow - mnew);  // 0 when mrow = -inf
    float psum = 0.0f;
#pragma unroll
    for (int jj = 0; jj < 16; jj++) { s[jj] = __expf(s[jj] - mnew); psum += s[jj]; }
    psum += __shfl_xor(psum, 1);
    psum += __shfl_xor(psum, 2);
    lrow = lrow * scale + psum;
    mrow = mnew;
#pragma unroll
    for (int jj = 0; jj < 16; jj++) sP[rr * 64 + c16 + jj] = s[jj];
    __syncthreads();

    // acc = acc*scale + P @ V  (thread: row rr, dims c16..c16+15)
#pragma unroll
    for (int q = 0; q < 4; q++) acc4[q] *= scale;
#pragma unroll 8
    for (int j = 0; j < 64; ++j) {
      const float p = sP[rr * 64 + j];
      const f32x4* vv = (const f32x4*)(sV + j * 64 + c16);
#pragma unroll
      for (int q = 0; q < 4; q++) acc4[q] += p * vv[q];
    }
  }

  const float inv = 1.0f / lrow;
  ushort* yp = yb + (size_t)(b * TT + q0 + rr) * DDIM + h * 64 + c16;
#pragma unroll
  for (int q = 0; q < 4; q++) {
    ushort4 o = { f2b(acc4[q][0] * inv), f2b(acc4[q][1] * inv),
                  f2b(acc4[q][2] * inv), f2b(acc4[q][3] * inv) };
    *(ushort4*)(yp + q * 4) = o;
  }
}

// ---------- fused residual add + LayerNorm (wave per row) ----------
__global__ __launch_bounds__(256) void add_ln(const float* __restrict__ x,
                                              const float* __restrict__ y,
                                              const float* __restrict__ w,
                                              const float* __restrict__ bb,
                                              float* __restrict__ xo,
                                              ushort* __restrict__ xb) {
  const int row = blockIdx.x * 4 + (threadIdx.x >> 6);
  const int lane = threadIdx.x & 63;
  const size_t base = (size_t)row * DDIM + lane * 8;
  f32x4 a0 = *(const f32x4*)(x + base);
  f32x4 a1 = *(const f32x4*)(x + base + 4);
  if (y) {
    a0 += *(const f32x4*)(y + base);
    a1 += *(const f32x4*)(y + base + 4);
  }
  float s = (a0[0] + a0[1] + a0[2] + a0[3]) + (a1[0] + a1[1] + a1[2] + a1[3]);
  f32x4 q0 = a0 * a0, q1 = a1 * a1;
  float ss = (q0[0] + q0[1] + q0[2] + q0[3]) + (q1[0] + q1[1] + q1[2] + q1[3]);
#pragma unroll
  for (int o = 1; o < 64; o <<= 1) {
    s += __shfl_xor(s, o);
    ss += __shfl_xor(ss, o);
  }
  const float mu = s * (1.0f / DDIM);
  const float var = ss * (1.0f / DDIM) - mu * mu;
  const float rs = rsqrtf(var + 1e-5f);
  const int c = lane * 8;
  f32x4 w0 = *(const f32x4*)(w + c), w1 = *(const f32x4*)(w + c + 4);
  f32x4 b0 = *(const f32x4*)(bb + c), b1 = *(const f32x4*)(bb + c + 4);
  f32x4 o0 = (a0 - mu) * rs * w0 + b0;
  f32x4 o1 = (a1 - mu) * rs * w1 + b1;
  *(f32x4*)(xo + base) = o0;
  *(f32x4*)(xo + base + 4) = o1;
  ushort4 u0 = { f2b(o0[0]), f2b(o0[1]), f2b(o0[2]), f2b(o0[3]) };
  ushort4 u1 = { f2b(o1[0]), f2b(o1[1]), f2b(o1[2]), f2b(o1[3]) };
  *(ushort4*)(xb + base) = u0;
  *(ushort4*)(xb + base + 4) = u1;
}

// ---------- launch ----------
extern "C" void kernel_launch(void* const* d_in, const int* in_sizes, int n_in,
                              void* d_out, int out_size, void* d_ws, size_t ws_size,
                              hipStream_t stream) {
  const int*   idx  = (const int*)d_in[0];
  const float* wte  = (const float*)d_in[1];
  const float* wpe  = (const float*)d_in[2];
  const float* aw   = (const float*)d_in[3];
  const float* ab   = (const float*)d_in[4];
  const float* pw   = (const float*)d_in[5];
  const float* pb   = (const float*)d_in[6];
  const float* fw   = (const float*)d_in[7];
  const float* fb   = (const float*)d_in[8];
  const float* f2w  = (const float*)d_in[9];
  const float* f2bi = (const float*)d_in[10];
  const float* l1w  = (const float*)d_in[11];
  const float* l1b  = (const float*)d_in[12];
  const float* l2w  = (const float*)d_in[13];
  const float* l2b  = (const float*)d_in[14];
  const float* lnfw = (const float*)d_in[15];
  const float* lnfb = (const float*)d_in[16];

  char* ws = (char*)d_ws;
  size_t off = 0;
  auto take = [&](size_t bytes) -> void* {
    void* p = ws + off;
    off += (bytes + 255) & ~(size_t)255;
    return p;
  };
  ushort* wte_b = (ushort*)take((size_t)VV * DDIM * 2);
  ushort* aw_b  = (ushort*)take((size_t)LL * 3 * DDIM * DDIM * 2);
  ushort* pw_b  = (ushort*)take((size_t)LL * DDIM * DDIM * 2);
  ushort* fw_b  = (ushort*)take((size_t)LL * FF * DDIM * 2);
  ushort* f2w_b = (ushort*)take((size_t)LL * DDIM * FF * 2);
  float*  x     = (float*)take((size_t)MM * DDIM * 4);
  ushort* xb    = (ushort*)take((size_t)MM * DDIM * 2);
  ushort* qkv_b = (ushort*)take((size_t)MM * 3 * DDIM * 2);
  ushort* yb    = (ushort*)take((size_t)MM * DDIM * 2);
  float*  tmp   = (float*)take((size_t)MM * DDIM * 4);
  ushort* hb    = (ushort*)take((size_t)MM * FF * 2);

  auto cvt = [&](const float* in, ushort* out, size_t n) {
    cvt_bf16<<<dim3((unsigned)((n / 4 + 255) / 256)), dim3(256), 0, stream>>>(in, out, (int)n);
  };
  cvt(wte, wte_b, (size_t)VV * DDIM);
  cvt(aw,  aw_b,  (size_t)LL * 3 * DDIM * DDIM);
  cvt(pw,  pw_b,  (size_t)LL * DDIM * DDIM);
  cvt(fw,  fw_b,  (size_t)LL * FF * DDIM);
  cvt(f2w, f2w_b, (size_t)LL * DDIM * FF);

  embed_kernel<<<dim3(MM), dim3(128), 0, stream>>>(idx, wte, wpe, x, xb);

  for (int l = 0; l < LL; ++l) {
    gemm_bt<0, 1><<<dim3(12, 24), dim3(256), 0, stream>>>(
        xb, aw_b + (size_t)l * 3 * DDIM * DDIM, ab + (size_t)l * 3 * DDIM, qkv_b, 3 * DDIM, DDIM);
    attn_fwd<<<dim3(TT / 64, BB * 8), dim3(256), 0, stream>>>(qkv_b, yb);
    gemm_bt<0, 0><<<dim3(4, 24), dim3(256), 0, stream>>>(
        yb, pw_b + (size_t)l * DDIM * DDIM, pb + (size_t)l * DDIM, tmp, DDIM, DDIM);
    add_ln<<<dim3(MM / 4), dim3(256), 0, stream>>>(
        x, tmp, l1w + (size_t)l * DDIM, l1b + (size_t)l * DDIM, x, xb);
    gemm_bt<1, 1><<<dim3(16, 24), dim3(256), 0, stream>>>(
        xb, fw_b + (size_t)l * FF * DDIM, fb + (size_t)l * FF, hb, FF, DDIM);
    gemm_bt<0, 0><<<dim3(4, 24), dim3(256), 0, stream>>>(
        hb, f2w_b + (size_t)l * DDIM * FF, f2bi + (size_t)l * DDIM, tmp, DDIM, FF);
    add_ln<<<dim3(MM / 4), dim3(256), 0, stream>>>(
        x, tmp, l2w + (size_t)l * DDIM, l2b + (size_t)l * DDIM, x, xb);
  }
  add_ln<<<dim3(MM / 4), dim3(256), 0, stream>>>(x, nullptr, lnfw, lnfb, x, xb);

  gemm_bt<0, 0><<<dim3(VV / 128, 24), dim3(256), 0, stream>>>(
      xb, wte_b, nullptr, (float*)d_out, VV, DDIM);
}

// Round 2
// 1142.202 us; speedup vs baseline: 2.0231x; 2.0231x over previous
//
#include <hip/hip_runtime.h>
#include <hip/hip_bf16.h>

#define AS1 __attribute__((address_space(1)))
#define AS3 __attribute__((address_space(3)))

typedef __attribute__((ext_vector_type(8))) short short8;
typedef __attribute__((ext_vector_type(4))) float f32x4;

constexpr int BB = 4, TT = 768, DDIM = 512, LL = 6, VV = 50304, FF = 2048;
constexpr int MM = BB * TT;  // 3072 rows of the activation matrix

// ---------- helpers ----------
__device__ inline unsigned short f2b(float f) {
  union { float f; unsigned u; } a; a.f = f;
  unsigned u = a.u;
  return (unsigned short)((u + 0x7FFFu + ((u >> 16) & 1u)) >> 16);  // RNE
}
__device__ inline float b2f(unsigned short u) {
  union { unsigned u; float f; } a; a.u = ((unsigned)u) << 16; return a.f;
}

// ---------- f32 -> bf16 convert ----------
__global__ void cvt_bf16(const float* __restrict__ in, ushort* __restrict__ out, int n) {
  size_t i = ((size_t)blockIdx.x * 256 + threadIdx.x) * 4;
  if (i >= (size_t)n) return;
  float4 v = *(const float4*)(in + i);
  ushort4 o = { f2b(v.x), f2b(v.y), f2b(v.z), f2b(v.w) };
  *(ushort4*)(out + i) = o;
}

// ---------- embedding: x = wte[idx] + wpe[t] ----------
__global__ void embed_kernel(const int* __restrict__ idx, const float* __restrict__ wte,
                             const float* __restrict__ wpe, float* __restrict__ x,
                             ushort* __restrict__ xb) {
  int row = blockIdx.x;          // 0..MM-1  (= b*T + t)
  int t = row % TT;
  int tok = idx[row];
  int c = threadIdx.x * 4;       // 128 threads * 4 = 512
  float4 a = *(const float4*)(wte + (size_t)tok * DDIM + c);
  float4 p = *(const float4*)(wpe + (size_t)t * DDIM + c);
  a.x += p.x; a.y += p.y; a.z += p.z; a.w += p.w;
  *(float4*)(x + (size_t)row * DDIM + c) = a;
  ushort4 o = { f2b(a.x), f2b(a.y), f2b(a.z), f2b(a.w) };
  *(ushort4*)(xb + (size_t)row * DDIM + c) = o;
}

// ---------- GEMM: C[M,N] = A[M,K](bf16) * Bw[N,K]^T(bf16) + bias ----------
// 128xNT tile, BK=32, 4 waves (2x2), 16x16x32 bf16 MFMA.
// SWZ=1: 1D grid, XCD-chunked so blocks sharing a B-tile run on one XCD (head GEMM).
template <int RELU, int OUTBF16, int NT, int SWZ>
__global__ __launch_bounds__(256) void gemm_bt(
    const ushort* __restrict__ A, const ushort* __restrict__ Bw,
    const float* __restrict__ bias, void* __restrict__ Cv, int Ndim, int K) {
  __shared__ ushort sA[128 * 32];
  __shared__ ushort sB[NT * 32];
  const int tid = threadIdx.x;
  const int wid = tid >> 6, lane = tid & 63;
  int m0, n0;
  if (SWZ) {
    int id = blockIdx.x;
    int v = (id >> 3) + (id & 7) * ((int)gridDim.x >> 3);
    m0 = (v % 24) * 128;          // M=3072 -> 24 m-tiles; same-B blocks consecutive per XCD
    n0 = (v / 24) * NT;
  } else {
    m0 = blockIdx.y * 128;
    n0 = blockIdx.x * NT;
  }
  const int wm = (wid >> 1) * 64, wn = (wid & 1) * (NT / 2);

  f32x4 zero = {0.f, 0.f, 0.f, 0.f};
  f32x4 acc[4][4];
#pragma unroll
  for (int i = 0; i < 4; i++)
#pragma unroll
    for (int j = 0; j < 4; j++) acc[i][j] = zero;

  const int r4 = tid >> 2;          // staging row (0..63 per round)
  const int c8 = (tid & 3) * 8;     // bf16 element offset (16B chunk)
  const ushort* gA = A + (size_t)(m0 + r4) * K + c8;
  const ushort* gB = Bw + (size_t)(n0 + r4) * K + c8;
  const size_t K64 = (size_t)64 * K;

  ushort* sAw = sA + wid * 512;     // wave-uniform LDS staging base
  ushort* sBw = sB + wid * 512;

  const int fr = lane & 15;
  const int fk = (lane >> 4) * 8;
  const ushort* pa0 = sA + (wm + fr) * 32 + fk;
  const ushort* pb0 = sB + (wn + fr) * 32 + fk;

  const int nK = K >> 5;
  for (int kk = 0; kk < nK; ++kk) {
    const ushort* a0 = gA + kk * 32;
    const ushort* b0 = gB + kk * 32;
    __builtin_amdgcn_global_load_lds((const AS1 void*)a0,         (AS3 void*)sAw,          16, 0, 0);
    __builtin_amdgcn_global_load_lds((const AS1 void*)(a0 + K64), (AS3 void*)(sAw + 2048), 16, 0, 0);
    __builtin_amdgcn_global_load_lds((const AS1 void*)b0,         (AS3 void*)sBw,          16, 0, 0);
    if (NT == 128)
      __builtin_amdgcn_global_load_lds((const AS1 void*)(b0 + K64), (AS3 void*)(sBw + 2048), 16, 0, 0);
    __syncthreads();
    short8 af[4], bf[4];
#pragma unroll
    for (int i = 0; i < 4; i++) af[i] = *(const short8*)(pa0 + i * 16 * 32);
#pragma unroll
    for (int j = 0; j < NT / 32; j++) bf[j] = *(const short8*)(pb0 + j * 16 * 32);
#pragma unroll
    for (int i = 0; i < 4; i++)
#pragma unroll
      for (int j = 0; j < NT / 32; j++)
        acc[i][j] = __builtin_amdgcn_mfma_f32_16x16x32_bf16(af[i], bf[j], acc[i][j], 0, 0, 0);
    __syncthreads();
  }

  // epilogue: C/D layout col=lane&15, row=(lane>>4)*4+reg
  const int cr = (lane >> 4) * 4;
  const int cc = lane & 15;
#pragma unroll
  for (int j = 0; j < NT / 32; j++) {
    const int gcol = n0 + wn + j * 16 + cc;
    const float bv = bias ? bias[gcol] : 0.0f;
#pragma unroll
    for (int i = 0; i < 4; i++) {
      const int grow = m0 + wm + i * 16 + cr;
#pragma unroll
      for (int rr = 0; rr < 4; ++rr) {
        float v = acc[i][j][rr] + bv;
        if (RELU) v = fmaxf(v, 0.0f);
        if (OUTBF16)
          ((ushort*)Cv)[(size_t)(grow + rr) * Ndim + gcol] = f2b(v);
        else
          ((float*)Cv)[(size_t)(grow + rr) * Ndim + gcol] = v;
      }
    }
  }
}

// ---------- MFMA fused causal attention ----------
// grid: (T/64, B*8); 256 threads = 4 waves; wave w owns q-rows [q0+16w, q0+16w+16).
// Frag layouts (16x16x32 bf16): A/B per-lane row|col=lane&15, k=(lane>>4)*8+i;
// C/D col=lane&15, row=(lane>>4)*4+reg.
__device__ inline short8 lds_swz_read(const ushort* base, int row, int elem) {
  return *(const short8*)((const char*)base + row * 128 + ((elem * 2) ^ ((row & 7) << 4)));
}

__global__ __launch_bounds__(256) void attn_mfma(const ushort* __restrict__ qkv,
                                                 ushort* __restrict__ yb) {
  __shared__ ushort sK[64 * 64];        // [krow][d], XOR-swizzled rows
  __shared__ ushort sVT[64 * 64];       // [d][krow], XOR-swizzled rows
  __shared__ ushort sP[4 * 16 * 64];    // per-wave [q][k], XOR-swizzled rows
  const int tid = threadIdx.x;
  const int wid = tid >> 6, lane = tid & 63;
  const int qt = blockIdx.x;
  const int b = blockIdx.y >> 3, h = blockIdx.y & 7;
  const int q0 = qt * 64;
  const int qw = q0 + wid * 16;

  const int fr = lane & 15;
  const int fk = (lane >> 4) * 8;
  ushort* sPw = sP + wid * 16 * 64;

  // Q fragments in registers (rows qw+fr, d = c*32+fk .. +8)
  short8 qf[2];
  {
    const ushort* qp = qkv + (size_t)(b * TT + qw + fr) * 1536 + h * 64;
    qf[0] = *(const short8*)(qp + fk);
    qf[1] = *(const short8*)(qp + 32 + fk);
  }

  const int r4 = tid >> 2;           // staging row 0..63
  const int c32 = (tid & 3) * 16;    // element offset (16 bf16 = 32B)

  f32x4 zero = {0.f, 0.f, 0.f, 0.f};
  f32x4 acc[4] = {zero, zero, zero, zero};
  float mrow[4] = {-INFINITY, -INFINITY, -INFINITY, -INFINITY};
  float lrow[4] = {0.f, 0.f, 0.f, 0.f};

  for (int kt = 0; kt <= qt; ++kt) {
    __syncthreads();  // prior tile's sK/sVT readers done
    const int k0 = kt * 64;
    {  // stage K tile (swizzled b128 writes) and V^T tile (scalar scatter)
      const ushort* kp = qkv + (size_t)(b * TT + k0 + r4) * 1536 + 512 + h * 64 + c32;
      short8 kv0 = *(const short8*)kp;
      short8 kv1 = *(const short8*)(kp + 8);
      char* skb = (char*)sK + r4 * 128;
      *(short8*)(skb + ((c32 * 2) ^ ((r4 & 7) << 4))) = kv0;
      *(short8*)(skb + ((c32 * 2 + 16) ^ ((r4 & 7) << 4))) = kv1;
      const ushort* vp = kp + 512;
      short8 vv0 = *(const short8*)vp;
      short8 vv1 = *(const short8*)(vp + 8);
#pragma unroll
      for (int i = 0; i < 8; i++) {
        int d0 = c32 + i, d1 = c32 + 8 + i;
        *(ushort*)((char*)sVT + d0 * 128 + ((r4 * 2) ^ ((d0 & 7) << 4))) = (ushort)vv0[i];
        *(ushort*)((char*)sVT + d1 * 128 + ((r4 * 2) ^ ((d1 & 7) << 4))) = (ushort)vv1[i];
      }
    }
    __syncthreads();

    // S = Q K^T * 0.125  -> 4 frags over k-cols
    f32x4 sfr[4];
#pragma unroll
    for (int j = 0; j < 4; j++) {
      short8 kb0 = lds_swz_read(sK, j * 16 + fr, fk);
      short8 kb1 = lds_swz_read(sK, j * 16 + fr, 32 + fk);
      f32x4 s = __builtin_amdgcn_mfma_f32_16x16x32_bf16(qf[0], kb0, zero, 0, 0, 0);
      s = __builtin_amdgcn_mfma_f32_16x16x32_bf16(qf[1], kb1, s, 0, 0, 0);
      sfr[j] = s * 0.125f;
    }
    if (kt == qt) {  // causal mask on diagonal tile
#pragma unroll
      for (int j = 0; j < 4; j++)
#pragma unroll
        for (int rr = 0; rr < 4; ++rr)
          if (j * 16 + fr > wid * 16 + (lane >> 4) * 4 + rr) sfr[j][rr] = -INFINITY;
    }

    // online softmax per q-row (4 rows/lane; k spread over 16 lanes + 4 frags)
    float scl[4];
#pragma unroll
    for (int rr = 0; rr < 4; ++rr) {
      float t = fmaxf(fmaxf(sfr[0][rr], sfr[1][rr]), fmaxf(sfr[2][rr], sfr[3][rr]));
      t = fmaxf(t, __shfl_xor(t, 1));
      t = fmaxf(t, __shfl_xor(t, 2));
      t = fmaxf(t, __shfl_xor(t, 4));
      t = fmaxf(t, __shfl_xor(t, 8));
      const float mnew = fmaxf(mrow[rr], t);
      scl[rr] = __expf(mrow[rr] - mnew);
      mrow[rr] = mnew;
      float ps = 0.f;
#pragma unroll
      for (int j = 0; j < 4; j++) {
        float p = __expf(sfr[j][rr] - mnew);
        sfr[j][rr] = p;
        ps += p;
      }
      ps += __shfl_xor(ps, 1);
      ps += __shfl_xor(ps, 2);
      ps += __shfl_xor(ps, 4);
      ps += __shfl_xor(ps, 8);
      lrow[rr] = lrow[rr] * scl[rr] + ps;
    }

    // P -> per-wave LDS (bf16, swizzled), then consume as A-frags
#pragma unroll
    for (int j = 0; j < 4; j++)
#pragma unroll
      for (int rr = 0; rr < 4; ++rr) {
        int q = (lane >> 4) * 4 + rr, k = j * 16 + fr;
        *(ushort*)((char*)sPw + q * 128 + ((k * 2) ^ ((q & 7) << 4))) = f2b(sfr[j][rr]);
      }

#pragma unroll
    for (int f = 0; f < 4; f++)
#pragma unroll
      for (int rr = 0; rr < 4; ++rr) acc[f][rr] *= scl[rr];

    short8 pa0 = lds_swz_read(sPw, fr, fk);
    short8 pa1 = lds_swz_read(sPw, fr, 32 + fk);
#pragma unroll
    for (int f = 0; f < 4; f++) {
      short8 vb0 = lds_swz_read(sVT, f * 16 + fr, fk);
      short8 vb1 = lds_swz_read(sVT, f * 16 + fr, 32 + fk);
      acc[f] = __builtin_amdgcn_mfma_f32_16x16x32_bf16(pa0, vb0, acc[f], 0, 0, 0);
      acc[f] = __builtin_amdgcn_mfma_f32_16x16x32_bf16(pa1, vb1, acc[f], 0, 0, 0);
    }
  }

  // epilogue: O[q][d] / l  -> yb[token][h*64+d]
#pragma unroll
  for (int rr = 0; rr < 4; ++rr) {
    const float inv = 1.0f / lrow[rr];
    const int token = b * TT + qw + (lane >> 4) * 4 + rr;
    ushort* yp = yb + (size_t)token * DDIM + h * 64 + fr;
#pragma unroll
    for (int f = 0; f < 4; f++) yp[f * 16] = f2b(acc[f][rr] * inv);
  }
}

// ---------- fused residual add + LayerNorm (wave per row) ----------
__global__ __launch_bounds__(256) void add_ln(const float* __restrict__ x,
                                              const float* __restrict__ y,
                                              const float* __restrict__ w,
                                              const float* __restrict__ bb,
                                              float* __restrict__ xo,
                                              ushort* __restrict__ xb) {
  const int row = blockIdx.x * 4 + (threadIdx.x >> 6);
  const int lane = threadIdx.x & 63;
  const size_t base = (size_t)row * DDIM + lane * 8;
  f32x4 a0 = *(const f32x4*)(x + base);
  f32x4 a1 = *(const f32x4*)(x + base + 4);
  if (y) {
    a0 += *(const f32x4*)(y + base);
    a1 += *(const f32x4*)(y + base + 4);
  }
  float s = (a0[0] + a0[1] + a0[2] + a0[3]) + (a1[0] + a1[1] + a1[2] + a1[3]);
  f32x4 q0 = a0 * a0, q1 = a1 * a1;
  float ss = (q0[0] + q0[1] + q0[2] + q0[3]) + (q1[0] + q1[1] + q1[2] + q1[3]);
#pragma unroll
  for (int o = 1; o < 64; o <<= 1) {
    s += __shfl_xor(s, o);
    ss += __shfl_xor(ss, o);
  }
  const float mu = s * (1.0f / DDIM);
  const float var = ss * (1.0f / DDIM) - mu * mu;
  const float rs = rsqrtf(var + 1e-5f);
  const int c = lane * 8;
  f32x4 w0 = *(const f32x4*)(w + c), w1 = *(const f32x4*)(w + c + 4);
  f32x4 b0 = *(const f32x4*)(bb + c), b1 = *(const f32x4*)(bb + c + 4);
  f32x4 o0 = (a0 - mu) * rs * w0 + b0;
  f32x4 o1 = (a1 - mu) * rs * w1 + b1;
  *(f32x4*)(xo + base) = o0;
  *(f32x4*)(xo + base + 4) = o1;
  ushort4 u0 = { f2b(o0[0]), f2b(o0[1]), f2b(o0[2]), f2b(o0[3]) };
  ushort4 u1 = { f2b(o1[0]), f2b(o1[1]), f2b(o1[2]), f2b(o1[3]) };
  *(ushort4*)(xb + base) = u0;
  *(ushort4*)(xb + base + 4) = u1;
}

// ---------- launch ----------
extern "C" void kernel_launch(void* const* d_in, const int* in_sizes, int n_in,
                              void* d_out, int out_size, void* d_ws, size_t ws_size,
                              hipStream_t stream) {
  const int*   idx  = (const int*)d_in[0];
  const float* wte  = (const float*)d_in[1];
  const float* wpe  = (const float*)d_in[2];
  const float* aw   = (const float*)d_in[3];
  const float* ab   = (const float*)d_in[4];
  const float* pw   = (const float*)d_in[5];
  const float* pb   = (const float*)d_in[6];
  const float* fw   = (const float*)d_in[7];
  const float* fb   = (const float*)d_in[8];
  const float* f2w  = (const float*)d_in[9];
  const float* f2bi = (const float*)d_in[10];
  const float* l1w  = (const float*)d_in[11];
  const float* l1b  = (const float*)d_in[12];
  const float* l2w  = (const float*)d_in[13];
  const float* l2b  = (const float*)d_in[14];
  const float* lnfw = (const float*)d_in[15];
  const float* lnfb = (const float*)d_in[16];

  char* ws = (char*)d_ws;
  size_t off = 0;
  auto take = [&](size_t bytes) -> void* {
    void* p = ws + off;
    off += (bytes + 255) & ~(size_t)255;
    return p;
  };
  ushort* wte_b = (ushort*)take((size_t)VV * DDIM * 2);
  ushort* aw_b  = (ushort*)take((size_t)LL * 3 * DDIM * DDIM * 2);
  ushort* pw_b  = (ushort*)take((size_t)LL * DDIM * DDIM * 2);
  ushort* fw_b  = (ushort*)take((size_t)LL * FF * DDIM * 2);
  ushort* f2w_b = (ushort*)take((size_t)LL * DDIM * FF * 2);
  float*  x     = (float*)take((size_t)MM * DDIM * 4);
  ushort* xb    = (ushort*)take((size_t)MM * DDIM * 2);
  ushort* qkv_b = (ushort*)take((size_t)MM * 3 * DDIM * 2);
  ushort* yb    = (ushort*)take((size_t)MM * DDIM * 2);
  float*  tmp   = (float*)take((size_t)MM * DDIM * 4);
  ushort* hb    = (ushort*)take((size_t)MM * FF * 2);

  auto cvt = [&](const float* in, ushort* out, size_t n) {
    cvt_bf16<<<dim3((unsigned)((n / 4 + 255) / 256)), dim3(256), 0, stream>>>(in, out, (int)n);
  };
  cvt(wte, wte_b, (size_t)VV * DDIM);
  cvt(aw,  aw_b,  (size_t)LL * 3 * DDIM * DDIM);
  cvt(pw,  pw_b,  (size_t)LL * DDIM * DDIM);
  cvt(fw,  fw_b,  (size_t)LL * FF * DDIM);
  cvt(f2w, f2w_b, (size_t)LL * DDIM * FF);

  embed_kernel<<<dim3(MM), dim3(128), 0, stream>>>(idx, wte, wpe, x, xb);

  for (int l = 0; l < LL; ++l) {
    gemm_bt<0, 1, 128, 0><<<dim3(12, 24), dim3(256), 0, stream>>>(
        xb, aw_b + (size_t)l * 3 * DDIM * DDIM, ab + (size_t)l * 3 * DDIM, qkv_b, 3 * DDIM, DDIM);
    attn_mfma<<<dim3(TT / 64, BB * 8), dim3(256), 0, stream>>>(qkv_b, yb);
    gemm_bt<0, 0, 64, 0><<<dim3(8, 24), dim3(256), 0, stream>>>(
        yb, pw_b + (size_t)l * DDIM * DDIM, pb + (size_t)l * DDIM, tmp, DDIM, DDIM);
    add_ln<<<dim3(MM / 4), dim3(256), 0, stream>>>(
        x, tmp, l1w + (size_t)l * DDIM, l1b + (size_t)l * DDIM, x, xb);
    gemm_bt<1, 1, 128, 0><<<dim3(16, 24), dim3(256), 0, stream>>>(
        xb, fw_b + (size_t)l * FF * DDIM, fb + (size_t)l * FF, hb, FF, DDIM);
    gemm_bt<0, 0, 64, 0><<<dim3(8, 24), dim3(256), 0, stream>>>(
        hb, f2w_b + (size_t)l * DDIM * FF, f2bi + (size_t)l * DDIM, tmp, DDIM, FF);
    add_ln<<<dim3(MM / 4), dim3(256), 0, stream>>>(
        x, tmp, l2w + (size_t)l * DDIM, l2b + (size_t)l * DDIM, x, xb);
  }
  add_ln<<<dim3(MM / 4), dim3(256), 0, stream>>>(x, nullptr, lnfw, lnfb, x, xb);

  gemm_bt<0, 0, 128, 1><<<dim3((VV / 128) * 24), dim3(256), 0, stream>>>(
      xb, wte_b, nullptr, (float*)d_out, VV, DDIM);
}

// Round 3
// 1028.013 us; speedup vs baseline: 2.2478x; 1.1111x over previous
//
#include <hip/hip_runtime.h>
#include <hip/hip_bf16.h>

#define AS1 __attribute__((address_space(1)))
#define AS3 __attribute__((address_space(3)))

typedef __attribute__((ext_vector_type(8))) short short8;
typedef __attribute__((ext_vector_type(4))) float f32x4;

constexpr int BB = 4, TT = 768, DDIM = 512, LL = 6, VV = 50304, FF = 2048;
constexpr int MM = BB * TT;  // 3072 rows of the activation matrix

// ---------- helpers ----------
__device__ inline unsigned short f2b(float f) {
  union { float f; unsigned u; } a; a.f = f;
  unsigned u = a.u;
  return (unsigned short)((u + 0x7FFFu + ((u >> 16) & 1u)) >> 16);  // RNE
}
__device__ inline float b2f(unsigned short u) {
  union { unsigned u; float f; } a; a.u = ((unsigned)u) << 16; return a.f;
}

// ---------- fused f32 -> bf16 convert of all 5 weight tensors ----------
// dst regions are contiguous in ws (each size is a multiple of 256 B).
constexpr size_t CW0 = (size_t)VV * DDIM;                 // wte
constexpr size_t CW1 = CW0 + (size_t)LL * 3 * DDIM * DDIM; // + c_attn_w
constexpr size_t CW2 = CW1 + (size_t)LL * DDIM * DDIM;     // + c_proj_w
constexpr size_t CW3 = CW2 + (size_t)LL * FF * DDIM;       // + fc_w
constexpr size_t CW4 = CW3 + (size_t)LL * DDIM * FF;       // + fc2_w

__global__ void cvt_all(const float* __restrict__ wte, const float* __restrict__ aw,
                        const float* __restrict__ pw, const float* __restrict__ fw,
                        const float* __restrict__ f2w, ushort* __restrict__ out) {
  size_t i = ((size_t)blockIdx.x * 256 + threadIdx.x) * 4;
  if (i >= CW4) return;
  const float* src; size_t base;
  if (i < CW0)      { src = wte; base = 0; }
  else if (i < CW1) { src = aw;  base = CW0; }
  else if (i < CW2) { src = pw;  base = CW1; }
  else if (i < CW3) { src = fw;  base = CW2; }
  else              { src = f2w; base = CW3; }
  float4 v = *(const float4*)(src + (i - base));
  ushort4 o = { f2b(v.x), f2b(v.y), f2b(v.z), f2b(v.w) };
  *(ushort4*)(out + i) = o;
}

// ---------- embedding: x = wte[idx] + wpe[t] ----------
__global__ void embed_kernel(const int* __restrict__ idx, const float* __restrict__ wte,
                             const float* __restrict__ wpe, float* __restrict__ x,
                             ushort* __restrict__ xb) {
  int row = blockIdx.x;          // 0..MM-1  (= b*T + t)
  int t = row % TT;
  int tok = idx[row];
  int c = threadIdx.x * 4;       // 128 threads * 4 = 512
  float4 a = *(const float4*)(wte + (size_t)tok * DDIM + c);
  float4 p = *(const float4*)(wpe + (size_t)t * DDIM + c);
  a.x += p.x; a.y += p.y; a.z += p.z; a.w += p.w;
  *(float4*)(x + (size_t)row * DDIM + c) = a;
  ushort4 o = { f2b(a.x), f2b(a.y), f2b(a.z), f2b(a.w) };
  *(ushort4*)(xb + (size_t)row * DDIM + c) = o;
}

// ---------- GEMM: C[M,N] = A[M,K](bf16) * Bw[N,K]^T(bf16) + bias ----------
// BMxBN tile, BK=32, 4 waves (2x2), 16x16x32 bf16 MFMA.
// Double-buffered LDS with prefetch (T3-minimum 2-phase): stage(t+1) issued
// BEFORE compute(t); single vmcnt-drain+barrier per K-step.
// SWZ=1: 1D grid, XCD-chunked so blocks sharing a B-tile run on one XCD.
template <int RELU, int OUTBF16, int BM, int BN, int SWZ>
__global__ __launch_bounds__(256) void gemm_bt(
    const ushort* __restrict__ A, const ushort* __restrict__ Bw,
    const float* __restrict__ bias, void* __restrict__ Cv, int Ndim, int K) {
  constexpr int MI = BM / 32, NJ = BN / 32;
  __shared__ ushort sA[2][BM * 32];
  __shared__ ushort sB[2][BN * 32];
  const int tid = threadIdx.x;
  const int wid = tid >> 6, lane = tid & 63;
  int m0, n0;
  if (SWZ) {
    constexpr int MT = MM / BM;
    int id = blockIdx.x;
    int v = (id >> 3) + (id & 7) * ((int)gridDim.x >> 3);
    m0 = (v % MT) * BM;           // same-B blocks consecutive per XCD
    n0 = (v / MT) * BN;
  } else {
    m0 = blockIdx.y * BM;
    n0 = blockIdx.x * BN;
  }
  const int wm = (wid >> 1) * (BM / 2), wn = (wid & 1) * (BN / 2);

  f32x4 zero = {0.f, 0.f, 0.f, 0.f};
  f32x4 acc[MI][NJ];
#pragma unroll
  for (int i = 0; i < MI; i++)
#pragma unroll
    for (int j = 0; j < NJ; j++) acc[i][j] = zero;

  const int r4 = tid >> 2;          // staging row (0..63 per call)
  const int c8 = (tid & 3) * 8;     // bf16 element offset (16B chunk)
  const ushort* gA = A + (size_t)(m0 + r4) * K + c8;
  const ushort* gB = Bw + (size_t)(n0 + r4) * K + c8;
  const size_t K64 = (size_t)64 * K;

  const int fr = lane & 15;
  const int fk = (lane >> 4) * 8;

  auto stage = [&](int buf, int kk) {
    const ushort* a0 = gA + kk * 32;
    const ushort* b0 = gB + kk * 32;
    ushort* dA = &sA[buf][0] + wid * 512;   // wave-uniform LDS base
    ushort* dB = &sB[buf][0] + wid * 512;
#pragma unroll
    for (int i = 0; i < BM / 64; i++)
      __builtin_amdgcn_global_load_lds((const AS1 void*)(a0 + (size_t)i * K64),
                                       (AS3 void*)(dA + i * 2048), 16, 0, 0);
#pragma unroll
    for (int i = 0; i < BN / 64; i++)
      __builtin_amdgcn_global_load_lds((const AS1 void*)(b0 + (size_t)i * K64),
                                       (AS3 void*)(dB + i * 2048), 16, 0, 0);
  };

  const int nK = K >> 5;
  stage(0, 0);
  __syncthreads();
  int buf = 0;
  for (int kk = 0; kk < nK; ++kk) {
    if (kk + 1 < nK) stage(buf ^ 1, kk + 1);   // prefetch flies under compute
    const ushort* pa0 = &sA[buf][0] + (wm + fr) * 32 + fk;
    const ushort* pb0 = &sB[buf][0] + (wn + fr) * 32 + fk;
    short8 af[MI], bf[NJ];
#pragma unroll
    for (int i = 0; i < MI; i++) af[i] = *(const short8*)(pa0 + i * 16 * 32);
#pragma unroll
    for (int j = 0; j < NJ; j++) bf[j] = *(const short8*)(pb0 + j * 16 * 32);
#pragma unroll
    for (int i = 0; i < MI; i++)
#pragma unroll
      for (int j = 0; j < NJ; j++)
        acc[i][j] = __builtin_amdgcn_mfma_f32_16x16x32_bf16(af[i], bf[j], acc[i][j], 0, 0, 0);
    __syncthreads();   // drains prefetch (vmcnt0) + protects buf swap
    buf ^= 1;
  }

  // epilogue: C/D layout col=lane&15, row=(lane>>4)*4+reg
  const int cr = (lane >> 4) * 4;
  const int cc = lane & 15;
#pragma unroll
  for (int j = 0; j < NJ; j++) {
    const int gcol = n0 + wn + j * 16 + cc;
    const float bv = bias ? bias[gcol] : 0.0f;
#pragma unroll
    for (int i = 0; i < MI; i++) {
      const int grow = m0 + wm + i * 16 + cr;
#pragma unroll
      for (int rr = 0; rr < 4; ++rr) {
        float v = acc[i][j][rr] + bv;
        if (RELU) v = fmaxf(v, 0.0f);
        if (OUTBF16)
          ((ushort*)Cv)[(size_t)(grow + rr) * Ndim + gcol] = f2b(v);
        else
          ((float*)Cv)[(size_t)(grow + rr) * Ndim + gcol] = v;
      }
    }
  }
}

// ---------- MFMA fused causal attention ----------
// grid: (T/64, B*8); 256 threads = 4 waves; wave w owns q-rows [q0+16w, q0+16w+16).
__device__ inline short8 lds_swz_read(const ushort* base, int row, int elem) {
  return *(const short8*)((const char*)base + row * 128 + ((elem * 2) ^ ((row & 7) << 4)));
}

__global__ __launch_bounds__(256) void attn_mfma(const ushort* __restrict__ qkv,
                                                 ushort* __restrict__ yb) {
  __shared__ ushort sK[64 * 64];        // [krow][d], XOR-swizzled rows
  __shared__ ushort sVT[64 * 64];       // [d][krow], XOR-swizzled rows
  __shared__ ushort sP[4 * 16 * 64];    // per-wave [q][k], XOR-swizzled rows
  const int tid = threadIdx.x;
  const int wid = tid >> 6, lane = tid & 63;
  const int qt = blockIdx.x;
  const int b = blockIdx.y >> 3, h = blockIdx.y & 7;
  const int q0 = qt * 64;
  const int qw = q0 + wid * 16;

  const int fr = lane & 15;
  const int fk = (lane >> 4) * 8;
  ushort* sPw = sP + wid * 16 * 64;

  // Q fragments in registers (rows qw+fr, d = c*32+fk .. +8)
  short8 qf[2];
  {
    const ushort* qp = qkv + (size_t)(b * TT + qw + fr) * 1536 + h * 64;
    qf[0] = *(const short8*)(qp + fk);
    qf[1] = *(const short8*)(qp + 32 + fk);
  }

  const int r4 = tid >> 2;           // staging row 0..63
  const int c32 = (tid & 3) * 16;    // element offset (16 bf16 = 32B)

  f32x4 zero = {0.f, 0.f, 0.f, 0.f};
  f32x4 acc[4] = {zero, zero, zero, zero};
  float mrow[4] = {-INFINITY, -INFINITY, -INFINITY, -INFINITY};
  float lrow[4] = {0.f, 0.f, 0.f, 0.f};

  for (int kt = 0; kt <= qt; ++kt) {
    __syncthreads();  // prior tile's sK/sVT readers done
    const int k0 = kt * 64;
    {  // stage K tile (swizzled b128 writes) and V^T tile (scalar scatter)
      const ushort* kp = qkv + (size_t)(b * TT + k0 + r4) * 1536 + 512 + h * 64 + c32;
      short8 kv0 = *(const short8*)kp;
      short8 kv1 = *(const short8*)(kp + 8);
      char* skb = (char*)sK + r4 * 128;
      *(short8*)(skb + ((c32 * 2) ^ ((r4 & 7) << 4))) = kv0;
      *(short8*)(skb + ((c32 * 2 + 16) ^ ((r4 & 7) << 4))) = kv1;
      const ushort* vp = kp + 512;
      short8 vv0 = *(const short8*)vp;
      short8 vv1 = *(const short8*)(vp + 8);
#pragma unroll
      for (int i = 0; i < 8; i++) {
        int d0 = c32 + i, d1 = c32 + 8 + i;
        *(ushort*)((char*)sVT + d0 * 128 + ((r4 * 2) ^ ((d0 & 7) << 4))) = (ushort)vv0[i];
        *(ushort*)((char*)sVT + d1 * 128 + ((r4 * 2) ^ ((d1 & 7) << 4))) = (ushort)vv1[i];
      }
    }
    __syncthreads();

    // S = Q K^T * 0.125  -> 4 frags over k-cols
    f32x4 sfr[4];
#pragma unroll
    for (int j = 0; j < 4; j++) {
      short8 kb0 = lds_swz_read(sK, j * 16 + fr, fk);
      short8 kb1 = lds_swz_read(sK, j * 16 + fr, 32 + fk);
      f32x4 s = __builtin_amdgcn_mfma_f32_16x16x32_bf16(qf[0], kb0, zero, 0, 0, 0);
      s = __builtin_amdgcn_mfma_f32_16x16x32_bf16(qf[1], kb1, s, 0, 0, 0);
      sfr[j] = s * 0.125f;
    }
    if (kt == qt) {  // causal mask on diagonal tile
#pragma unroll
      for (int j = 0; j < 4; j++)
#pragma unroll
        for (int rr = 0; rr < 4; ++rr)
          if (j * 16 + fr > wid * 16 + (lane >> 4) * 4 + rr) sfr[j][rr] = -INFINITY;
    }

    // online softmax per q-row (4 rows/lane; k spread over 16 lanes + 4 frags)
    float scl[4];
#pragma unroll
    for (int rr = 0; rr < 4; ++rr) {
      float t = fmaxf(fmaxf(sfr[0][rr], sfr[1][rr]), fmaxf(sfr[2][rr], sfr[3][rr]));
      t = fmaxf(t, __shfl_xor(t, 1));
      t = fmaxf(t, __shfl_xor(t, 2));
      t = fmaxf(t, __shfl_xor(t, 4));
      t = fmaxf(t, __shfl_xor(t, 8));
      const float mnew = fmaxf(mrow[rr], t);
      scl[rr] = __expf(mrow[rr] - mnew);
      mrow[rr] = mnew;
      float ps = 0.f;
#pragma unroll
      for (int j = 0; j < 4; j++) {
        float p = __expf(sfr[j][rr] - mnew);
        sfr[j][rr] = p;
        ps += p;
      }
      ps += __shfl_xor(ps, 1);
      ps += __shfl_xor(ps, 2);
      ps += __shfl_xor(ps, 4);
      ps += __shfl_xor(ps, 8);
      lrow[rr] = lrow[rr] * scl[rr] + ps;
    }

    // P -> per-wave LDS (bf16, swizzled), then consume as A-frags
#pragma unroll
    for (int j = 0; j < 4; j++)
#pragma unroll
      for (int rr = 0; rr < 4; ++rr) {
        int q = (lane >> 4) * 4 + rr, k = j * 16 + fr;
        *(ushort*)((char*)sPw + q * 128 + ((k * 2) ^ ((q & 7) << 4))) = f2b(sfr[j][rr]);
      }

#pragma unroll
    for (int f = 0; f < 4; f++)
#pragma unroll
      for (int rr = 0; rr < 4; ++rr) acc[f][rr] *= scl[rr];

    short8 pa0 = lds_swz_read(sPw, fr, fk);
    short8 pa1 = lds_swz_read(sPw, fr, 32 + fk);
#pragma unroll
    for (int f = 0; f < 4; f++) {
      short8 vb0 = lds_swz_read(sVT, f * 16 + fr, fk);
      short8 vb1 = lds_swz_read(sVT, f * 16 + fr, 32 + fk);
      acc[f] = __builtin_amdgcn_mfma_f32_16x16x32_bf16(pa0, vb0, acc[f], 0, 0, 0);
      acc[f] = __builtin_amdgcn_mfma_f32_16x16x32_bf16(pa1, vb1, acc[f], 0, 0, 0);
    }
  }

  // epilogue: O[q][d] / l  -> yb[token][h*64+d]
#pragma unroll
  for (int rr = 0; rr < 4; ++rr) {
    const float inv = 1.0f / lrow[rr];
    const int token = b * TT + qw + (lane >> 4) * 4 + rr;
    ushort* yp = yb + (size_t)token * DDIM + h * 64 + fr;
#pragma unroll
    for (int f = 0; f < 4; f++) yp[f * 16] = f2b(acc[f][rr] * inv);
  }
}

// ---------- fused residual add + LayerNorm (wave per row) ----------
__global__ __launch_bounds__(256) void add_ln(const float* __restrict__ x,
                                              const float* __restrict__ y,
                                              const float* __restrict__ w,
                                              const float* __restrict__ bb,
                                              float* __restrict__ xo,
                                              ushort* __restrict__ xb) {
  const int row = blockIdx.x * 4 + (threadIdx.x >> 6);
  const int lane = threadIdx.x & 63;
  const size_t base = (size_t)row * DDIM + lane * 8;
  f32x4 a0 = *(const f32x4*)(x + base);
  f32x4 a1 = *(const f32x4*)(x + base + 4);
  if (y) {
    a0 += *(const f32x4*)(y + base);
    a1 += *(const f32x4*)(y + base + 4);
  }
  float s = (a0[0] + a0[1] + a0[2] + a0[3]) + (a1[0] + a1[1] + a1[2] + a1[3]);
  f32x4 q0 = a0 * a0, q1 = a1 * a1;
  float ss = (q0[0] + q0[1] + q0[2] + q0[3]) + (q1[0] + q1[1] + q1[2] + q1[3]);
#pragma unroll
  for (int o = 1; o < 64; o <<= 1) {
    s += __shfl_xor(s, o);
    ss += __shfl_xor(ss, o);
  }
  const float mu = s * (1.0f / DDIM);
  const float var = ss * (1.0f / DDIM) - mu * mu;
  const float rs = rsqrtf(var + 1e-5f);
  const int c = lane * 8;
  f32x4 w0 = *(const f32x4*)(w + c), w1 = *(const f32x4*)(w + c + 4);
  f32x4 b0 = *(const f32x4*)(bb + c), b1 = *(const f32x4*)(bb + c + 4);
  f32x4 o0 = (a0 - mu) * rs * w0 + b0;
  f32x4 o1 = (a1 - mu) * rs * w1 + b1;
  *(f32x4*)(xo + base) = o0;
  *(f32x4*)(xo + base + 4) = o1;
  ushort4 u0 = { f2b(o0[0]), f2b(o0[1]), f2b(o0[2]), f2b(o0[3]) };
  ushort4 u1 = { f2b(o1[0]), f2b(o1[1]), f2b(o1[2]), f2b(o1[3]) };
  *(ushort4*)(xb + base) = u0;
  *(ushort4*)(xb + base + 4) = u1;
}

// ---------- launch ----------
extern "C" void kernel_launch(void* const* d_in, const int* in_sizes, int n_in,
                              void* d_out, int out_size, void* d_ws, size_t ws_size,
                              hipStream_t stream) {
  const int*   idx  = (const int*)d_in[0];
  const float* wte  = (const float*)d_in[1];
  const float* wpe  = (const float*)d_in[2];
  const float* aw   = (const float*)d_in[3];
  const float* ab   = (const float*)d_in[4];
  const float* pw   = (const float*)d_in[5];
  const float* pb   = (const float*)d_in[6];
  const float* fw   = (const float*)d_in[7];
  const float* fb   = (const float*)d_in[8];
  const float* f2w  = (const float*)d_in[9];
  const float* f2bi = (const float*)d_in[10];
  const float* l1w  = (const float*)d_in[11];
  const float* l1b  = (const float*)d_in[12];
  const float* l2w  = (const float*)d_in[13];
  const float* l2b  = (const float*)d_in[14];
  const float* lnfw = (const float*)d_in[15];
  const float* lnfb = (const float*)d_in[16];

  char* ws = (char*)d_ws;
  size_t off = 0;
  auto take = [&](size_t bytes) -> void* {
    void* p = ws + off;
    off += (bytes + 255) & ~(size_t)255;
    return p;
  };
  // weight bf16 regions are contiguous (each size is a multiple of 256 B)
  ushort* wte_b = (ushort*)take((size_t)VV * DDIM * 2);
  ushort* aw_b  = (ushort*)take((size_t)LL * 3 * DDIM * DDIM * 2);
  ushort* pw_b  = (ushort*)take((size_t)LL * DDIM * DDIM * 2);
  ushort* fw_b  = (ushort*)take((size_t)LL * FF * DDIM * 2);
  ushort* f2w_b = (ushort*)take((size_t)LL * DDIM * FF * 2);
  float*  x     = (float*)take((size_t)MM * DDIM * 4);
  ushort* xb    = (ushort*)take((size_t)MM * DDIM * 2);
  ushort* qkv_b = (ushort*)take((size_t)MM * 3 * DDIM * 2);
  ushort* yb    = (ushort*)take((size_t)MM * DDIM * 2);
  float*  tmp   = (float*)take((size_t)MM * DDIM * 4);
  ushort* hb    = (ushort*)take((size_t)MM * FF * 2);

  cvt_all<<<dim3((unsigned)(CW4 / 4 / 256)), dim3(256), 0, stream>>>(
      wte, aw, pw, fw, f2w, wte_b);

  embed_kernel<<<dim3(MM), dim3(128), 0, stream>>>(idx, wte, wpe, x, xb);

  for (int l = 0; l < LL; ++l) {
    gemm_bt<0, 1, 128, 64, 0><<<dim3(24, 24), dim3(256), 0, stream>>>(
        xb, aw_b + (size_t)l * 3 * DDIM * DDIM, ab + (size_t)l * 3 * DDIM, qkv_b, 3 * DDIM, DDIM);
    attn_mfma<<<dim3(TT / 64, BB * 8), dim3(256), 0, stream>>>(qkv_b, yb);
    gemm_bt<0, 0, 64, 64, 0><<<dim3(8, 48), dim3(256), 0, stream>>>(
        yb, pw_b + (size_t)l * DDIM * DDIM, pb + (size_t)l * DDIM, tmp, DDIM, DDIM);
    add_ln<<<dim3(MM / 4), dim3(256), 0, stream>>>(
        x, tmp, l1w + (size_t)l * DDIM, l1b + (size_t)l * DDIM, x, xb);
    gemm_bt<1, 1, 128, 64, 0><<<dim3(32, 24), dim3(256), 0, stream>>>(
        xb, fw_b + (size_t)l * FF * DDIM, fb + (size_t)l * FF, hb, FF, DDIM);
    gemm_bt<0, 0, 64, 64, 0><<<dim3(8, 48), dim3(256), 0, stream>>>(
        hb, f2w_b + (size_t)l * DDIM * FF, f2bi + (size_t)l * DDIM, tmp, DDIM, FF);
    add_ln<<<dim3(MM / 4), dim3(256), 0, stream>>>(
        x, tmp, l2w + (size_t)l * DDIM, l2b + (size_t)l * DDIM, x, xb);
  }
  add_ln<<<dim3(MM / 4), dim3(256), 0, stream>>>(x, nullptr, lnfw, lnfb, x, xb);

  gemm_bt<0, 0, 128, 128, 1><<<dim3((VV / 128) * 24), dim3(256), 0, stream>>>(
      xb, wte_b, nullptr, (float*)d_out, VV, DDIM);
}

// Round 4
// 901.110 us; speedup vs baseline: 2.5644x; 1.1408x over previous
//
#include <hip/hip_runtime.h>
#include <hip/hip_bf16.h>

#define AS1 __attribute__((address_space(1)))
#define AS3 __attribute__((address_space(3)))

typedef __attribute__((ext_vector_type(8))) short short8;
typedef __attribute__((ext_vector_type(4))) float f32x4;

constexpr int BB = 4, TT = 768, DDIM = 512, LL = 6, VV = 50304, FF = 2048;
constexpr int MM = BB * TT;  // 3072 rows of the activation matrix

// ---------- helpers ----------
__device__ inline unsigned short f2b(float f) {
  union { float f; unsigned u; } a; a.f = f;
  unsigned u = a.u;
  return (unsigned short)((u + 0x7FFFu + ((u >> 16) & 1u)) >> 16);  // RNE
}
__device__ inline float b2f(unsigned short u) {
  union { unsigned u; float f; } a; a.u = ((unsigned)u) << 16; return a.f;
}

// ---------- fused f32 -> bf16 convert of all 5 weight tensors ----------
constexpr size_t CW0 = (size_t)VV * DDIM;                  // wte
constexpr size_t CW1 = CW0 + (size_t)LL * 3 * DDIM * DDIM; // + c_attn_w
constexpr size_t CW2 = CW1 + (size_t)LL * DDIM * DDIM;     // + c_proj_w
constexpr size_t CW3 = CW2 + (size_t)LL * FF * DDIM;       // + fc_w
constexpr size_t CW4 = CW3 + (size_t)LL * DDIM * FF;       // + fc2_w

__global__ void cvt_all(const float* __restrict__ wte, const float* __restrict__ aw,
                        const float* __restrict__ pw, const float* __restrict__ fw,
                        const float* __restrict__ f2w, ushort* __restrict__ out) {
  size_t i = ((size_t)blockIdx.x * 256 + threadIdx.x) * 4;
  if (i >= CW4) return;
  const float* src; size_t base;
  if (i < CW0)      { src = wte; base = 0; }
  else if (i < CW1) { src = aw;  base = CW0; }
  else if (i < CW2) { src = pw;  base = CW1; }
  else if (i < CW3) { src = fw;  base = CW2; }
  else              { src = f2w; base = CW3; }
  float4 v = *(const float4*)(src + (i - base));
  ushort4 o = { f2b(v.x), f2b(v.y), f2b(v.z), f2b(v.w) };
  *(ushort4*)(out + i) = o;
}

// ---------- embedding: x = wte[idx] + wpe[t] ----------
__global__ void embed_kernel(const int* __restrict__ idx, const float* __restrict__ wte,
                             const float* __restrict__ wpe, float* __restrict__ x,
                             ushort* __restrict__ xb) {
  int row = blockIdx.x;
  int t = row % TT;
  int tok = idx[row];
  int c = threadIdx.x * 4;
  float4 a = *(const float4*)(wte + (size_t)tok * DDIM + c);
  float4 p = *(const float4*)(wpe + (size_t)t * DDIM + c);
  a.x += p.x; a.y += p.y; a.z += p.z; a.w += p.w;
  *(float4*)(x + (size_t)row * DDIM + c) = a;
  ushort4 o = { f2b(a.x), f2b(a.y), f2b(a.z), f2b(a.w) };
  *(ushort4*)(xb + (size_t)row * DDIM + c) = o;
}

// ---------- layer GEMM: BK=64, swizzled LDS, dbuf 2-phase, optional split-K ----
// C[M,N] (or partial plane z) = A[M,K-chunk] * Bw[N,K-chunk]^T (+ bias on z==0)
// LDS layout: row-major [row][64 bf16 = 128B], byte swizzle: slot ^= (row&7).
// global_load_lds writes linearly (lane*16B) so the GLOBAL source chunk is
// inverse-swizzled per-lane (rule #21: both-sides-or-neither).
template <int RELU, int OUTBF16, int BM, int BN, int SPLITK>
__global__ __launch_bounds__(256) void gemm_bt64(
    const ushort* __restrict__ A, const ushort* __restrict__ Bw,
    const float* __restrict__ bias, void* __restrict__ Cv, int Ndim, int K) {
  constexpr int MI = BM / 32, NJ = BN / 32;
  __shared__ ushort sA[2][BM * 64];
  __shared__ ushort sB[2][BN * 64];
  const int tid = threadIdx.x;
  const int wid = tid >> 6, lane = tid & 63;
  const int m0 = blockIdx.y * BM, n0 = blockIdx.x * BN;
  const int kchunk = K / SPLITK;
  const int ks0 = (SPLITK > 1) ? blockIdx.z * kchunk : 0;
  const int wm = (wid >> 1) * (BM / 2), wn = (wid & 1) * (BN / 2);

  f32x4 zero = {0.f, 0.f, 0.f, 0.f};
  f32x4 acc[MI][NJ];
#pragma unroll
  for (int i = 0; i < MI; i++)
#pragma unroll
    for (int j = 0; j < NJ; j++) acc[i][j] = zero;

  // staging: thread t -> row r=t>>3 (of 32/pass), slot t&7; global chunk inv-swizzled
  const int r = tid >> 3;
  const int cg = ((tid & 7) ^ (r & 7)) * 8;
  const ushort* gA = A + (size_t)(m0 + r) * K + ks0 + cg;
  const ushort* gB = Bw + (size_t)(n0 + r) * K + ks0 + cg;

  auto stage = [&](int buf, int kk) {
    const ushort* a0 = gA + kk * 64;
    const ushort* b0 = gB + kk * 64;
    ushort* dA = &sA[buf][0] + wid * 512;   // wave-uniform base; HW adds lane*16B
    ushort* dB = &sB[buf][0] + wid * 512;
#pragma unroll
    for (int p = 0; p < BM / 32; p++)
      __builtin_amdgcn_global_load_lds((const AS1 void*)(a0 + (size_t)p * 32 * K),
                                       (AS3 void*)(dA + p * 2048), 16, 0, 0);
#pragma unroll
    for (int p = 0; p < BN / 32; p++)
      __builtin_amdgcn_global_load_lds((const AS1 void*)(b0 + (size_t)p * 32 * K),
                                       (AS3 void*)(dB + p * 2048), 16, 0, 0);
  };

  const int fr = lane & 15;
  const int fk = (lane >> 4) * 8;
  auto ldfrag = [&](const ushort* s, int rowbase, int sub) -> short8 {
    const int row = rowbase + fr;
    const int off = row * 128 + ((sub * 64 + fk * 2) ^ ((fr & 7) << 4));
    return *(const short8*)((const char*)s + off);
  };

  const int nK = kchunk >> 6;
  stage(0, 0);
  __syncthreads();
  int buf = 0;
  for (int kk = 0; kk < nK; ++kk) {
    if (kk + 1 < nK) stage(buf ^ 1, kk + 1);
    short8 af[MI][2], bf[NJ][2];
#pragma unroll
    for (int i = 0; i < MI; i++)
#pragma unroll
      for (int s = 0; s < 2; s++) af[i][s] = ldfrag(&sA[buf][0], wm + i * 16, s);
#pragma unroll
    for (int j = 0; j < NJ; j++)
#pragma unroll
      for (int s = 0; s < 2; s++) bf[j][s] = ldfrag(&sB[buf][0], wn + j * 16, s);
#pragma unroll
    for (int i = 0; i < MI; i++)
#pragma unroll
      for (int j = 0; j < NJ; j++)
#pragma unroll
        for (int s = 0; s < 2; s++)
          acc[i][j] = __builtin_amdgcn_mfma_f32_16x16x32_bf16(af[i][s], bf[j][s], acc[i][j], 0, 0, 0);
    __syncthreads();
    buf ^= 1;
  }

  const int cr = (lane >> 4) * 4;
  const int cc = lane & 15;
  float* Cf = (float*)Cv + (SPLITK > 1 ? (size_t)blockIdx.z * MM * Ndim : 0);
#pragma unroll
  for (int j = 0; j < NJ; j++) {
    const int gcol = n0 + wn + j * 16 + cc;
    const float bv = (bias && (SPLITK == 1 || blockIdx.z == 0)) ? bias[gcol] : 0.0f;
#pragma unroll
    for (int i = 0; i < MI; i++) {
      const int grow = m0 + wm + i * 16 + cr;
#pragma unroll
      for (int rr = 0; rr < 4; ++rr) {
        float v = acc[i][j][rr] + bv;
        if (RELU) v = fmaxf(v, 0.0f);
        if (OUTBF16)
          ((ushort*)Cv)[(size_t)(grow + rr) * Ndim + gcol] = f2b(v);
        else
          Cf[(size_t)(grow + rr) * Ndim + gcol] = v;
      }
    }
  }
}

// ---------- head GEMM (BK=32, 128x128, XCD-swizzled, dbuf 2-phase) ----------
__global__ __launch_bounds__(256) void gemm_head(
    const ushort* __restrict__ A, const ushort* __restrict__ Bw,
    float* __restrict__ Cv, int Ndim, int K) {
  __shared__ ushort sA[2][128 * 32];
  __shared__ ushort sB[2][128 * 32];
  const int tid = threadIdx.x;
  const int wid = tid >> 6, lane = tid & 63;
  int id = blockIdx.x;
  int v = (id >> 3) + (id & 7) * ((int)gridDim.x >> 3);
  const int m0 = (v % 24) * 128;       // same-B blocks consecutive per XCD
  const int n0 = (v / 24) * 128;
  const int wm = (wid >> 1) * 64, wn = (wid & 1) * 64;

  f32x4 zero = {0.f, 0.f, 0.f, 0.f};
  f32x4 acc[4][4];
#pragma unroll
  for (int i = 0; i < 4; i++)
#pragma unroll
    for (int j = 0; j < 4; j++) acc[i][j] = zero;

  const int r4 = tid >> 2;
  const int c8 = (tid & 3) * 8;
  const ushort* gA = A + (size_t)(m0 + r4) * K + c8;
  const ushort* gB = Bw + (size_t)(n0 + r4) * K + c8;
  const size_t K64 = (size_t)64 * K;

  auto stage = [&](int buf, int kk) {
    const ushort* a0 = gA + kk * 32;
    const ushort* b0 = gB + kk * 32;
    ushort* dA = &sA[buf][0] + wid * 512;
    ushort* dB = &sB[buf][0] + wid * 512;
#pragma unroll
    for (int i = 0; i < 2; i++)
      __builtin_amdgcn_global_load_lds((const AS1 void*)(a0 + (size_t)i * K64),
                                       (AS3 void*)(dA + i * 2048), 16, 0, 0);
#pragma unroll
    for (int i = 0; i < 2; i++)
      __builtin_amdgcn_global_load_lds((const AS1 void*)(b0 + (size_t)i * K64),
                                       (AS3 void*)(dB + i * 2048), 16, 0, 0);
  };

  const int fr = lane & 15;
  const int fk = (lane >> 4) * 8;
  const int nK = K >> 5;
  stage(0, 0);
  __syncthreads();
  int buf = 0;
  for (int kk = 0; kk < nK; ++kk) {
    if (kk + 1 < nK) stage(buf ^ 1, kk + 1);
    const ushort* pa0 = &sA[buf][0] + (wm + fr) * 32 + fk;
    const ushort* pb0 = &sB[buf][0] + (wn + fr) * 32 + fk;
    short8 af[4], bf[4];
#pragma unroll
    for (int i = 0; i < 4; i++) af[i] = *(const short8*)(pa0 + i * 16 * 32);
#pragma unroll
    for (int j = 0; j < 4; j++) bf[j] = *(const short8*)(pb0 + j * 16 * 32);
#pragma unroll
    for (int i = 0; i < 4; i++)
#pragma unroll
      for (int j = 0; j < 4; j++)
        acc[i][j] = __builtin_amdgcn_mfma_f32_16x16x32_bf16(af[i], bf[j], acc[i][j], 0, 0, 0);
    __syncthreads();
    buf ^= 1;
  }

  const int cr = (lane >> 4) * 4;
  const int cc = lane & 15;
#pragma unroll
  for (int j = 0; j < 4; j++) {
    const int gcol = n0 + wn + j * 16 + cc;
#pragma unroll
    for (int i = 0; i < 4; i++) {
      const int grow = m0 + wm + i * 16 + cr;
#pragma unroll
      for (int rr = 0; rr < 4; ++rr)
        Cv[(size_t)(grow + rr) * Ndim + gcol] = acc[i][j][rr];
    }
  }
}

// ---------- MFMA fused causal attention ----------
__device__ inline short8 lds_swz_read(const ushort* base, int row, int elem) {
  return *(const short8*)((const char*)base + row * 128 + ((elem * 2) ^ ((row & 7) << 4)));
}

__global__ __launch_bounds__(256) void attn_mfma(const ushort* __restrict__ qkv,
                                                 ushort* __restrict__ yb) {
  __shared__ ushort sK[64 * 64];
  __shared__ ushort sVT[64 * 64];
  __shared__ ushort sP[4 * 16 * 64];
  const int tid = threadIdx.x;
  const int wid = tid >> 6, lane = tid & 63;
  const int qt = blockIdx.x;
  const int b = blockIdx.y >> 3, h = blockIdx.y & 7;
  const int q0 = qt * 64;
  const int qw = q0 + wid * 16;

  const int fr = lane & 15;
  const int fk = (lane >> 4) * 8;
  ushort* sPw = sP + wid * 16 * 64;

  short8 qf[2];
  {
    const ushort* qp = qkv + (size_t)(b * TT + qw + fr) * 1536 + h * 64;
    qf[0] = *(const short8*)(qp + fk);
    qf[1] = *(const short8*)(qp + 32 + fk);
  }

  const int r4 = tid >> 2;
  const int c32 = (tid & 3) * 16;

  f32x4 zero = {0.f, 0.f, 0.f, 0.f};
  f32x4 acc[4] = {zero, zero, zero, zero};
  float mrow[4] = {-INFINITY, -INFINITY, -INFINITY, -INFINITY};
  float lrow[4] = {0.f, 0.f, 0.f, 0.f};

  for (int kt = 0; kt <= qt; ++kt) {
    __syncthreads();
    const int k0 = kt * 64;
    {
      const ushort* kp = qkv + (size_t)(b * TT + k0 + r4) * 1536 + 512 + h * 64 + c32;
      short8 kv0 = *(const short8*)kp;
      short8 kv1 = *(const short8*)(kp + 8);
      char* skb = (char*)sK + r4 * 128;
      *(short8*)(skb + ((c32 * 2) ^ ((r4 & 7) << 4))) = kv0;
      *(short8*)(skb + ((c32 * 2 + 16) ^ ((r4 & 7) << 4))) = kv1;
      const ushort* vp = kp + 512;
      short8 vv0 = *(const short8*)vp;
      short8 vv1 = *(const short8*)(vp + 8);
#pragma unroll
      for (int i = 0; i < 8; i++) {
        int d0 = c32 + i, d1 = c32 + 8 + i;
        *(ushort*)((char*)sVT + d0 * 128 + ((r4 * 2) ^ ((d0 & 7) << 4))) = (ushort)vv0[i];
        *(ushort*)((char*)sVT + d1 * 128 + ((r4 * 2) ^ ((d1 & 7) << 4))) = (ushort)vv1[i];
      }
    }
    __syncthreads();

    f32x4 sfr[4];
#pragma unroll
    for (int j = 0; j < 4; j++) {
      short8 kb0 = lds_swz_read(sK, j * 16 + fr, fk);
      short8 kb1 = lds_swz_read(sK, j * 16 + fr, 32 + fk);
      f32x4 s = __builtin_amdgcn_mfma_f32_16x16x32_bf16(qf[0], kb0, zero, 0, 0, 0);
      s = __builtin_amdgcn_mfma_f32_16x16x32_bf16(qf[1], kb1, s, 0, 0, 0);
      sfr[j] = s * 0.125f;
    }
    if (kt == qt) {
#pragma unroll
      for (int j = 0; j < 4; j++)
#pragma unroll
        for (int rr = 0; rr < 4; ++rr)
          if (j * 16 + fr > wid * 16 + (lane >> 4) * 4 + rr) sfr[j][rr] = -INFINITY;
    }

    float scl[4];
#pragma unroll
    for (int rr = 0; rr < 4; ++rr) {
      float t = fmaxf(fmaxf(sfr[0][rr], sfr[1][rr]), fmaxf(sfr[2][rr], sfr[3][rr]));
      t = fmaxf(t, __shfl_xor(t, 1));
      t = fmaxf(t, __shfl_xor(t, 2));
      t = fmaxf(t, __shfl_xor(t, 4));
      t = fmaxf(t, __shfl_xor(t, 8));
      const float mnew = fmaxf(mrow[rr], t);
      scl[rr] = __expf(mrow[rr] - mnew);
      mrow[rr] = mnew;
      float ps = 0.f;
#pragma unroll
      for (int j = 0; j < 4; j++) {
        float p = __expf(sfr[j][rr] - mnew);
        sfr[j][rr] = p;
        ps += p;
      }
      ps += __shfl_xor(ps, 1);
      ps += __shfl_xor(ps, 2);
      ps += __shfl_xor(ps, 4);
      ps += __shfl_xor(ps, 8);
      lrow[rr] = lrow[rr] * scl[rr] + ps;
    }

#pragma unroll
    for (int j = 0; j < 4; j++)
#pragma unroll
      for (int rr = 0; rr < 4; ++rr) {
        int q = (lane >> 4) * 4 + rr, k = j * 16 + fr;
        *(ushort*)((char*)sPw + q * 128 + ((k * 2) ^ ((q & 7) << 4))) = f2b(sfr[j][rr]);
      }

#pragma unroll
    for (int f = 0; f < 4; f++)
#pragma unroll
      for (int rr = 0; rr < 4; ++rr) acc[f][rr] *= scl[rr];

    short8 pa0 = lds_swz_read(sPw, fr, fk);
    short8 pa1 = lds_swz_read(sPw, fr, 32 + fk);
#pragma unroll
    for (int f = 0; f < 4; f++) {
      short8 vb0 = lds_swz_read(sVT, f * 16 + fr, fk);
      short8 vb1 = lds_swz_read(sVT, f * 16 + fr, 32 + fk);
      acc[f] = __builtin_amdgcn_mfma_f32_16x16x32_bf16(pa0, vb0, acc[f], 0, 0, 0);
      acc[f] = __builtin_amdgcn_mfma_f32_16x16x32_bf16(pa1, vb1, acc[f], 0, 0, 0);
    }
  }

#pragma unroll
  for (int rr = 0; rr < 4; ++rr) {
    const float inv = 1.0f / lrow[rr];
    const int token = b * TT + qw + (lane >> 4) * 4 + rr;
    ushort* yp = yb + (size_t)token * DDIM + h * 64 + fr;
#pragma unroll
    for (int f = 0; f < 4; f++) yp[f * 16] = f2b(acc[f][rr] * inv);
  }
}

// ---------- fused residual add (+ S split-K partial planes) + LayerNorm ----------
template <int S>
__global__ __launch_bounds__(256) void add_ln(const float* __restrict__ x,
                                              const float* __restrict__ y,
                                              const float* __restrict__ w,
                                              const float* __restrict__ bb,
                                              float* __restrict__ xo,
                                              ushort* __restrict__ xb) {
  const int row = blockIdx.x * 4 + (threadIdx.x >> 6);
  const int lane = threadIdx.x & 63;
  const size_t base = (size_t)row * DDIM + lane * 8;
  f32x4 a0 = *(const f32x4*)(x + base);
  f32x4 a1 = *(const f32x4*)(x + base + 4);
#pragma unroll
  for (int s = 0; s < S; ++s) {
    a0 += *(const f32x4*)(y + (size_t)s * MM * DDIM + base);
    a1 += *(const f32x4*)(y + (size_t)s * MM * DDIM + base + 4);
  }
  float sm = (a0[0] + a0[1] + a0[2] + a0[3]) + (a1[0] + a1[1] + a1[2] + a1[3]);
  f32x4 q0 = a0 * a0, q1 = a1 * a1;
  float ss = (q0[0] + q0[1] + q0[2] + q0[3]) + (q1[0] + q1[1] + q1[2] + q1[3]);
#pragma unroll
  for (int o = 1; o < 64; o <<= 1) {
    sm += __shfl_xor(sm, o);
    ss += __shfl_xor(ss, o);
  }
  const float mu = sm * (1.0f / DDIM);
  const float var = ss * (1.0f / DDIM) - mu * mu;
  const float rs = rsqrtf(var + 1e-5f);
  const int c = lane * 8;
  f32x4 w0 = *(const f32x4*)(w + c), w1 = *(const f32x4*)(w + c + 4);
  f32x4 b0 = *(const f32x4*)(bb + c), b1 = *(const f32x4*)(bb + c + 4);
  f32x4 o0 = (a0 - mu) * rs * w0 + b0;
  f32x4 o1 = (a1 - mu) * rs * w1 + b1;
  *(f32x4*)(xo + base) = o0;
  *(f32x4*)(xo + base + 4) = o1;
  ushort4 u0 = { f2b(o0[0]), f2b(o0[1]), f2b(o0[2]), f2b(o0[3]) };
  ushort4 u1 = { f2b(o1[0]), f2b(o1[1]), f2b(o1[2]), f2b(o1[3]) };
  *(ushort4*)(xb + base) = u0;
  *(ushort4*)(xb + base + 4) = u1;
}

// ---------- launch ----------
extern "C" void kernel_launch(void* const* d_in, const int* in_sizes, int n_in,
                              void* d_out, int out_size, void* d_ws, size_t ws_size,
                              hipStream_t stream) {
  const int*   idx  = (const int*)d_in[0];
  const float* wte  = (const float*)d_in[1];
  const float* wpe  = (const float*)d_in[2];
  const float* aw   = (const float*)d_in[3];
  const float* ab   = (const float*)d_in[4];
  const float* pw   = (const float*)d_in[5];
  const float* pb   = (const float*)d_in[6];
  const float* fw   = (const float*)d_in[7];
  const float* fb   = (const float*)d_in[8];
  const float* f2w  = (const float*)d_in[9];
  const float* f2bi = (const float*)d_in[10];
  const float* l1w  = (const float*)d_in[11];
  const float* l1b  = (const float*)d_in[12];
  const float* l2w  = (const float*)d_in[13];
  const float* l2b  = (const float*)d_in[14];
  const float* lnfw = (const float*)d_in[15];
  const float* lnfb = (const float*)d_in[16];

  char* ws = (char*)d_ws;
  size_t off = 0;
  auto take = [&](size_t bytes) -> void* {
    void* p = ws + off;
    off += (bytes + 255) & ~(size_t)255;
    return p;
  };
  ushort* wte_b = (ushort*)take((size_t)VV * DDIM * 2);
  ushort* aw_b  = (ushort*)take((size_t)LL * 3 * DDIM * DDIM * 2);
  ushort* pw_b  = (ushort*)take((size_t)LL * DDIM * DDIM * 2);
  ushort* fw_b  = (ushort*)take((size_t)LL * FF * DDIM * 2);
  ushort* f2w_b = (ushort*)take((size_t)LL * DDIM * FF * 2);
  float*  x     = (float*)take((size_t)MM * DDIM * 4);
  ushort* xb    = (ushort*)take((size_t)MM * DDIM * 2);
  ushort* qkv_b = (ushort*)take((size_t)MM * 3 * DDIM * 2);
  ushort* yb    = (ushort*)take((size_t)MM * DDIM * 2);
  float*  tmp   = (float*)take((size_t)4 * MM * DDIM * 4);  // up to 4 split-K planes
  ushort* hb    = (ushort*)take((size_t)MM * FF * 2);

  cvt_all<<<dim3((unsigned)(CW4 / 4 / 256)), dim3(256), 0, stream>>>(
      wte, aw, pw, fw, f2w, wte_b);

  embed_kernel<<<dim3(MM), dim3(128), 0, stream>>>(idx, wte, wpe, x, xb);

  for (int l = 0; l < LL; ++l) {
    gemm_bt64<0, 1, 128, 64, 1><<<dim3(24, 24), dim3(256), 0, stream>>>(
        xb, aw_b + (size_t)l * 3 * DDIM * DDIM, ab + (size_t)l * 3 * DDIM, qkv_b, 3 * DDIM, DDIM);
    attn_mfma<<<dim3(TT / 64, BB * 8), dim3(256), 0, stream>>>(qkv_b, yb);
    gemm_bt64<0, 0, 64, 64, 2><<<dim3(8, 48, 2), dim3(256), 0, stream>>>(
        yb, pw_b + (size_t)l * DDIM * DDIM, pb + (size_t)l * DDIM, tmp, DDIM, DDIM);
    add_ln<2><<<dim3(MM / 4), dim3(256), 0, stream>>>(
        x, tmp, l1w + (size_t)l * DDIM, l1b + (size_t)l * DDIM, x, xb);
    gemm_bt64<1, 1, 128, 64, 1><<<dim3(32, 24), dim3(256), 0, stream>>>(
        xb, fw_b + (size_t)l * FF * DDIM, fb + (size_t)l * FF, hb, FF, DDIM);
    gemm_bt64<0, 0, 64, 64, 4><<<dim3(8, 48, 4), dim3(256), 0, stream>>>(
        hb, f2w_b + (size_t)l * DDIM * FF, f2bi + (size_t)l * DDIM, tmp, DDIM, FF);
    add_ln<4><<<dim3(MM / 4), dim3(256), 0, stream>>>(
        x, tmp, l2w + (size_t)l * DDIM, l2b + (size_t)l * DDIM, x, xb);
  }
  add_ln<0><<<dim3(MM / 4), dim3(256), 0, stream>>>(x, nullptr, lnfw, lnfb, x, xb);

  gemm_head<<<dim3((VV / 128) * 24), dim3(256), 0, stream>>>(
      xb, wte_b, (float*)d_out, VV, DDIM);
}

// Round 5
// 856.618 us; speedup vs baseline: 2.6976x; 1.0519x over previous
//
#include <hip/hip_runtime.h>
#include <hip/hip_bf16.h>

#define AS1 __attribute__((address_space(1)))
#define AS3 __attribute__((address_space(3)))

typedef __attribute__((ext_vector_type(8))) short short8;
typedef __attribute__((ext_vector_type(4))) float f32x4;

constexpr int BB = 4, TT = 768, DDIM = 512, LL = 6, VV = 50304, FF = 2048;
constexpr int MM = BB * TT;  // 3072 rows of the activation matrix

// ---------- helpers ----------
__device__ inline unsigned short f2b(float f) {
  union { float f; unsigned u; } a; a.f = f;
  unsigned u = a.u;
  return (unsigned short)((u + 0x7FFFu + ((u >> 16) & 1u)) >> 16);  // RNE
}
__device__ inline float b2f(unsigned short u) {
  union { unsigned u; float f; } a; a.u = ((unsigned)u) << 16; return a.f;
}

// ---------- fused f32 -> bf16 convert of all 5 weight tensors ----------
constexpr size_t CW0 = (size_t)VV * DDIM;                  // wte
constexpr size_t CW1 = CW0 + (size_t)LL * 3 * DDIM * DDIM; // + c_attn_w
constexpr size_t CW2 = CW1 + (size_t)LL * DDIM * DDIM;     // + c_proj_w
constexpr size_t CW3 = CW2 + (size_t)LL * FF * DDIM;       // + fc_w
constexpr size_t CW4 = CW3 + (size_t)LL * DDIM * FF;       // + fc2_w

__global__ void cvt_all(const float* __restrict__ wte, const float* __restrict__ aw,
                        const float* __restrict__ pw, const float* __restrict__ fw,
                        const float* __restrict__ f2w, ushort* __restrict__ out) {
  size_t i = ((size_t)blockIdx.x * 256 + threadIdx.x) * 4;
  if (i >= CW4) return;
  const float* src; size_t base;
  if (i < CW0)      { src = wte; base = 0; }
  else if (i < CW1) { src = aw;  base = CW0; }
  else if (i < CW2) { src = pw;  base = CW1; }
  else if (i < CW3) { src = fw;  base = CW2; }
  else              { src = f2w; base = CW3; }
  float4 v = *(const float4*)(src + (i - base));
  ushort4 o = { f2b(v.x), f2b(v.y), f2b(v.z), f2b(v.w) };
  *(ushort4*)(out + i) = o;
}

// ---------- embedding: x = wte[idx] + wpe[t] ----------
__global__ void embed_kernel(const int* __restrict__ idx, const float* __restrict__ wte,
                             const float* __restrict__ wpe, float* __restrict__ x,
                             ushort* __restrict__ xb) {
  int row = blockIdx.x;
  int t = row % TT;
  int tok = idx[row];
  int c = threadIdx.x * 4;
  float4 a = *(const float4*)(wte + (size_t)tok * DDIM + c);
  float4 p = *(const float4*)(wpe + (size_t)t * DDIM + c);
  a.x += p.x; a.y += p.y; a.z += p.z; a.w += p.w;
  *(float4*)(x + (size_t)row * DDIM + c) = a;
  ushort4 o = { f2b(a.x), f2b(a.y), f2b(a.z), f2b(a.w) };
  *(ushort4*)(xb + (size_t)row * DDIM + c) = o;
}

// ---------- layer GEMM: BK=64, swizzled LDS, dbuf 2-phase, optional split-K ----
// C[M,N] (or partial plane z) = A[M,K-chunk] * Bw[N,K-chunk]^T (+ bias on z==0)
// LDS layout: row-major [row][64 bf16 = 128B], byte swizzle: slot ^= (row&7).
// global_load_lds writes linearly (lane*16B) so the GLOBAL source chunk is
// inverse-swizzled per-lane (rule #21: both-sides-or-neither).
// Split-K partial planes are bf16 (post-LN normalization absorbs the rounding).
template <int RELU, int OUTBF16, int BM, int BN, int SPLITK>
__global__ __launch_bounds__(256) void gemm_bt64(
    const ushort* __restrict__ A, const ushort* __restrict__ Bw,
    const float* __restrict__ bias, void* __restrict__ Cv, int Ndim, int K) {
  constexpr int MI = BM / 32, NJ = BN / 32;
  __shared__ ushort sA[2][BM * 64];
  __shared__ ushort sB[2][BN * 64];
  const int tid = threadIdx.x;
  const int wid = tid >> 6, lane = tid & 63;
  const int m0 = blockIdx.y * BM, n0 = blockIdx.x * BN;
  const int kchunk = K / SPLITK;
  const int ks0 = (SPLITK > 1) ? blockIdx.z * kchunk : 0;
  const int wm = (wid >> 1) * (BM / 2), wn = (wid & 1) * (BN / 2);

  f32x4 zero = {0.f, 0.f, 0.f, 0.f};
  f32x4 acc[MI][NJ];
#pragma unroll
  for (int i = 0; i < MI; i++)
#pragma unroll
    for (int j = 0; j < NJ; j++) acc[i][j] = zero;

  // staging: thread t -> row r=t>>3 (of 32/pass), slot t&7; global chunk inv-swizzled
  const int r = tid >> 3;
  const int cg = ((tid & 7) ^ (r & 7)) * 8;
  const ushort* gA = A + (size_t)(m0 + r) * K + ks0 + cg;
  const ushort* gB = Bw + (size_t)(n0 + r) * K + ks0 + cg;

  auto stage = [&](int buf, int kk) {
    const ushort* a0 = gA + kk * 64;
    const ushort* b0 = gB + kk * 64;
    ushort* dA = &sA[buf][0] + wid * 512;   // wave-uniform base; HW adds lane*16B
    ushort* dB = &sB[buf][0] + wid * 512;
#pragma unroll
    for (int p = 0; p < BM / 32; p++)
      __builtin_amdgcn_global_load_lds((const AS1 void*)(a0 + (size_t)p * 32 * K),
                                       (AS3 void*)(dA + p * 2048), 16, 0, 0);
#pragma unroll
    for (int p = 0; p < BN / 32; p++)
      __builtin_amdgcn_global_load_lds((const AS1 void*)(b0 + (size_t)p * 32 * K),
                                       (AS3 void*)(dB + p * 2048), 16, 0, 0);
  };

  const int fr = lane & 15;
  const int fk = (lane >> 4) * 8;
  auto ldfrag = [&](const ushort* s, int rowbase, int sub) -> short8 {
    const int row = rowbase + fr;
    const int off = row * 128 + ((sub * 64 + fk * 2) ^ ((fr & 7) << 4));
    return *(const short8*)((const char*)s + off);
  };

  const int nK = kchunk >> 6;
  stage(0, 0);
  __syncthreads();
  int buf = 0;
  for (int kk = 0; kk < nK; ++kk) {
    if (kk + 1 < nK) stage(buf ^ 1, kk + 1);
    short8 af[MI][2], bf[NJ][2];
#pragma unroll
    for (int i = 0; i < MI; i++)
#pragma unroll
      for (int s = 0; s < 2; s++) af[i][s] = ldfrag(&sA[buf][0], wm + i * 16, s);
#pragma unroll
    for (int j = 0; j < NJ; j++)
#pragma unroll
      for (int s = 0; s < 2; s++) bf[j][s] = ldfrag(&sB[buf][0], wn + j * 16, s);
#pragma unroll
    for (int i = 0; i < MI; i++)
#pragma unroll
      for (int j = 0; j < NJ; j++)
#pragma unroll
        for (int s = 0; s < 2; s++)
          acc[i][j] = __builtin_amdgcn_mfma_f32_16x16x32_bf16(af[i][s], bf[j][s], acc[i][j], 0, 0, 0);
    __syncthreads();
    buf ^= 1;
  }

  const int cr = (lane >> 4) * 4;
  const int cc = lane & 15;
  const size_t zoff = (SPLITK > 1) ? (size_t)blockIdx.z * MM * Ndim : 0;
  ushort* Cb = (ushort*)Cv + zoff;
  float*  Cf = (float*)Cv + zoff;
#pragma unroll
  for (int j = 0; j < NJ; j++) {
    const int gcol = n0 + wn + j * 16 + cc;
    const float bv = (bias && (SPLITK == 1 || blockIdx.z == 0)) ? bias[gcol] : 0.0f;
#pragma unroll
    for (int i = 0; i < MI; i++) {
      const int grow = m0 + wm + i * 16 + cr;
#pragma unroll
      for (int rr = 0; rr < 4; ++rr) {
        float v = acc[i][j][rr] + bv;
        if (RELU) v = fmaxf(v, 0.0f);
        if (OUTBF16)
          Cb[(size_t)(grow + rr) * Ndim + gcol] = f2b(v);
        else
          Cf[(size_t)(grow + rr) * Ndim + gcol] = v;
      }
    }
  }
}

// ---------- head GEMM (BK=32, 128x128, XCD-swizzled, dbuf 2-phase) ----------
__global__ __launch_bounds__(256) void gemm_head(
    const ushort* __restrict__ A, const ushort* __restrict__ Bw,
    float* __restrict__ Cv, int Ndim, int K) {
  __shared__ ushort sA[2][128 * 32];
  __shared__ ushort sB[2][128 * 32];
  const int tid = threadIdx.x;
  const int wid = tid >> 6, lane = tid & 63;
  int id = blockIdx.x;
  int v = (id >> 3) + (id & 7) * ((int)gridDim.x >> 3);
  const int m0 = (v % 24) * 128;       // same-B blocks consecutive per XCD
  const int n0 = (v / 24) * 128;
  const int wm = (wid >> 1) * 64, wn = (wid & 1) * 64;

  f32x4 zero = {0.f, 0.f, 0.f, 0.f};
  f32x4 acc[4][4];
#pragma unroll
  for (int i = 0; i < 4; i++)
#pragma unroll
    for (int j = 0; j < 4; j++) acc[i][j] = zero;

  const int r4 = tid >> 2;
  const int c8 = (tid & 3) * 8;
  const ushort* gA = A + (size_t)(m0 + r4) * K + c8;
  const ushort* gB = Bw + (size_t)(n0 + r4) * K + c8;
  const size_t K64 = (size_t)64 * K;

  auto stage = [&](int buf, int kk) {
    const ushort* a0 = gA + kk * 32;
    const ushort* b0 = gB + kk * 32;
    ushort* dA = &sA[buf][0] + wid * 512;
    ushort* dB = &sB[buf][0] + wid * 512;
#pragma unroll
    for (int i = 0; i < 2; i++)
      __builtin_amdgcn_global_load_lds((const AS1 void*)(a0 + (size_t)i * K64),
                                       (AS3 void*)(dA + i * 2048), 16, 0, 0);
#pragma unroll
    for (int i = 0; i < 2; i++)
      __builtin_amdgcn_global_load_lds((const AS1 void*)(b0 + (size_t)i * K64),
                                       (AS3 void*)(dB + i * 2048), 16, 0, 0);
  };

  const int fr = lane & 15;
  const int fk = (lane >> 4) * 8;
  const int nK = K >> 5;
  stage(0, 0);
  __syncthreads();
  int buf = 0;
  for (int kk = 0; kk < nK; ++kk) {
    if (kk + 1 < nK) stage(buf ^ 1, kk + 1);
    const ushort* pa0 = &sA[buf][0] + (wm + fr) * 32 + fk;
    const ushort* pb0 = &sB[buf][0] + (wn + fr) * 32 + fk;
    short8 af[4], bf[4];
#pragma unroll
    for (int i = 0; i < 4; i++) af[i] = *(const short8*)(pa0 + i * 16 * 32);
#pragma unroll
    for (int j = 0; j < 4; j++) bf[j] = *(const short8*)(pb0 + j * 16 * 32);
#pragma unroll
    for (int i = 0; i < 4; i++)
#pragma unroll
      for (int j = 0; j < 4; j++)
        acc[i][j] = __builtin_amdgcn_mfma_f32_16x16x32_bf16(af[i], bf[j], acc[i][j], 0, 0, 0);
    __syncthreads();
    buf ^= 1;
  }

  const int cr = (lane >> 4) * 4;
  const int cc = lane & 15;
#pragma unroll
  for (int j = 0; j < 4; j++) {
    const int gcol = n0 + wn + j * 16 + cc;
#pragma unroll
    for (int i = 0; i < 4; i++) {
      const int grow = m0 + wm + i * 16 + cr;
#pragma unroll
      for (int rr = 0; rr < 4; ++rr)
        Cv[(size_t)(grow + rr) * Ndim + gcol] = acc[i][j][rr];
    }
  }
}

// ---------- MFMA fused causal attention ----------
__device__ inline short8 lds_swz_read(const ushort* base, int row, int elem) {
  return *(const short8*)((const char*)base + row * 128 + ((elem * 2) ^ ((row & 7) << 4)));
}

__global__ __launch_bounds__(256) void attn_mfma(const ushort* __restrict__ qkv,
                                                 ushort* __restrict__ yb) {
  __shared__ ushort sK[64 * 64];
  __shared__ ushort sVT[64 * 64];
  __shared__ ushort sP[4 * 16 * 64];
  const int tid = threadIdx.x;
  const int wid = tid >> 6, lane = tid & 63;
  const int qt = blockIdx.x;
  const int b = blockIdx.y >> 3, h = blockIdx.y & 7;
  const int q0 = qt * 64;
  const int qw = q0 + wid * 16;

  const int fr = lane & 15;
  const int fk = (lane >> 4) * 8;
  ushort* sPw = sP + wid * 16 * 64;

  short8 qf[2];
  {
    const ushort* qp = qkv + (size_t)(b * TT + qw + fr) * 1536 + h * 64;
    qf[0] = *(const short8*)(qp + fk);
    qf[1] = *(const short8*)(qp + 32 + fk);
  }

  const int r4 = tid >> 2;
  const int c32 = (tid & 3) * 16;

  f32x4 zero = {0.f, 0.f, 0.f, 0.f};
  f32x4 acc[4] = {zero, zero, zero, zero};
  float mrow[4] = {-INFINITY, -INFINITY, -INFINITY, -INFINITY};
  float lrow[4] = {0.f, 0.f, 0.f, 0.f};

  for (int kt = 0; kt <= qt; ++kt) {
    __syncthreads();
    const int k0 = kt * 64;
    {
      const ushort* kp = qkv + (size_t)(b * TT + k0 + r4) * 1536 + 512 + h * 64 + c32;
      short8 kv0 = *(const short8*)kp;
      short8 kv1 = *(const short8*)(kp + 8);
      char* skb = (char*)sK + r4 * 128;
      *(short8*)(skb + ((c32 * 2) ^ ((r4 & 7) << 4))) = kv0;
      *(short8*)(skb + ((c32 * 2 + 16) ^ ((r4 & 7) << 4))) = kv1;
      const ushort* vp = kp + 512;
      short8 vv0 = *(const short8*)vp;
      short8 vv1 = *(const short8*)(vp + 8);
#pragma unroll
      for (int i = 0; i < 8; i++) {
        int d0 = c32 + i, d1 = c32 + 8 + i;
        *(ushort*)((char*)sVT + d0 * 128 + ((r4 * 2) ^ ((d0 & 7) << 4))) = (ushort)vv0[i];
        *(ushort*)((char*)sVT + d1 * 128 + ((r4 * 2) ^ ((d1 & 7) << 4))) = (ushort)vv1[i];
      }
    }
    __syncthreads();

    f32x4 sfr[4];
#pragma unroll
    for (int j = 0; j < 4; j++) {
      short8 kb0 = lds_swz_read(sK, j * 16 + fr, fk);
      short8 kb1 = lds_swz_read(sK, j * 16 + fr, 32 + fk);
      f32x4 s = __builtin_amdgcn_mfma_f32_16x16x32_bf16(qf[0], kb0, zero, 0, 0, 0);
      s = __builtin_amdgcn_mfma_f32_16x16x32_bf16(qf[1], kb1, s, 0, 0, 0);
      sfr[j] = s * 0.125f;
    }
    if (kt == qt) {
#pragma unroll
      for (int j = 0; j < 4; j++)
#pragma unroll
        for (int rr = 0; rr < 4; ++rr)
          if (j * 16 + fr > wid * 16 + (lane >> 4) * 4 + rr) sfr[j][rr] = -INFINITY;
    }

    float scl[4];
#pragma unroll
    for (int rr = 0; rr < 4; ++rr) {
      float t = fmaxf(fmaxf(sfr[0][rr], sfr[1][rr]), fmaxf(sfr[2][rr], sfr[3][rr]));
      t = fmaxf(t, __shfl_xor(t, 1));
      t = fmaxf(t, __shfl_xor(t, 2));
      t = fmaxf(t, __shfl_xor(t, 4));
      t = fmaxf(t, __shfl_xor(t, 8));
      const float mnew = fmaxf(mrow[rr], t);
      scl[rr] = __expf(mrow[rr] - mnew);
      mrow[rr] = mnew;
      float ps = 0.f;
#pragma unroll
      for (int j = 0; j < 4; j++) {
        float p = __expf(sfr[j][rr] - mnew);
        sfr[j][rr] = p;
        ps += p;
      }
      ps += __shfl_xor(ps, 1);
      ps += __shfl_xor(ps, 2);
      ps += __shfl_xor(ps, 4);
      ps += __shfl_xor(ps, 8);
      lrow[rr] = lrow[rr] * scl[rr] + ps;
    }

#pragma unroll
    for (int j = 0; j < 4; j++)
#pragma unroll
      for (int rr = 0; rr < 4; ++rr) {
        int q = (lane >> 4) * 4 + rr, k = j * 16 + fr;
        *(ushort*)((char*)sPw + q * 128 + ((k * 2) ^ ((q & 7) << 4))) = f2b(sfr[j][rr]);
      }

#pragma unroll
    for (int f = 0; f < 4; f++)
#pragma unroll
      for (int rr = 0; rr < 4; ++rr) acc[f][rr] *= scl[rr];

    short8 pa0 = lds_swz_read(sPw, fr, fk);
    short8 pa1 = lds_swz_read(sPw, fr, 32 + fk);
#pragma unroll
    for (int f = 0; f < 4; f++) {
      short8 vb0 = lds_swz_read(sVT, f * 16 + fr, fk);
      short8 vb1 = lds_swz_read(sVT, f * 16 + fr, 32 + fk);
      acc[f] = __builtin_amdgcn_mfma_f32_16x16x32_bf16(pa0, vb0, acc[f], 0, 0, 0);
      acc[f] = __builtin_amdgcn_mfma_f32_16x16x32_bf16(pa1, vb1, acc[f], 0, 0, 0);
    }
  }

#pragma unroll
  for (int rr = 0; rr < 4; ++rr) {
    const float inv = 1.0f / lrow[rr];
    const int token = b * TT + qw + (lane >> 4) * 4 + rr;
    ushort* yp = yb + (size_t)token * DDIM + h * 64 + fr;
#pragma unroll
    for (int f = 0; f < 4; f++) yp[f * 16] = f2b(acc[f][rr] * inv);
  }
}

// ---------- fused residual add (+ S bf16 split-K partial planes) + LayerNorm ----
template <int S>
__global__ __launch_bounds__(256) void add_ln(const float* __restrict__ x,
                                              const ushort* __restrict__ y,
                                              const float* __restrict__ w,
                                              const float* __restrict__ bb,
                                              float* __restrict__ xo,
                                              ushort* __restrict__ xb) {
  const int row = blockIdx.x * 4 + (threadIdx.x >> 6);
  const int lane = threadIdx.x & 63;
  const size_t base = (size_t)row * DDIM + lane * 8;
  f32x4 a0 = *(const f32x4*)(x + base);
  f32x4 a1 = *(const f32x4*)(x + base + 4);
#pragma unroll
  for (int s = 0; s < S; ++s) {
    short8 v = *(const short8*)(y + (size_t)s * MM * DDIM + base);
    f32x4 p0 = { b2f((unsigned short)v[0]), b2f((unsigned short)v[1]),
                 b2f((unsigned short)v[2]), b2f((unsigned short)v[3]) };
    f32x4 p1 = { b2f((unsigned short)v[4]), b2f((unsigned short)v[5]),
                 b2f((unsigned short)v[6]), b2f((unsigned short)v[7]) };
    a0 += p0; a1 += p1;
  }
  float sm = (a0[0] + a0[1] + a0[2] + a0[3]) + (a1[0] + a1[1] + a1[2] + a1[3]);
  f32x4 q0 = a0 * a0, q1 = a1 * a1;
  float ss = (q0[0] + q0[1] + q0[2] + q0[3]) + (q1[0] + q1[1] + q1[2] + q1[3]);
#pragma unroll
  for (int o = 1; o < 64; o <<= 1) {
    sm += __shfl_xor(sm, o);
    ss += __shfl_xor(ss, o);
  }
  const float mu = sm * (1.0f / DDIM);
  const float var = ss * (1.0f / DDIM) - mu * mu;
  const float rs = rsqrtf(var + 1e-5f);
  const int c = lane * 8;
  f32x4 w0 = *(const f32x4*)(w + c), w1 = *(const f32x4*)(w + c + 4);
  f32x4 b0 = *(const f32x4*)(bb + c), b1 = *(const f32x4*)(bb + c + 4);
  f32x4 o0 = (a0 - mu) * rs * w0 + b0;
  f32x4 o1 = (a1 - mu) * rs * w1 + b1;
  *(f32x4*)(xo + base) = o0;
  *(f32x4*)(xo + base + 4) = o1;
  ushort4 u0 = { f2b(o0[0]), f2b(o0[1]), f2b(o0[2]), f2b(o0[3]) };
  ushort4 u1 = { f2b(o1[0]), f2b(o1[1]), f2b(o1[2]), f2b(o1[3]) };
  *(ushort4*)(xb + base) = u0;
  *(ushort4*)(xb + base + 4) = u1;
}

// ---------- launch ----------
extern "C" void kernel_launch(void* const* d_in, const int* in_sizes, int n_in,
                              void* d_out, int out_size, void* d_ws, size_t ws_size,
                              hipStream_t stream) {
  const int*   idx  = (const int*)d_in[0];
  const float* wte  = (const float*)d_in[1];
  const float* wpe  = (const float*)d_in[2];
  const float* aw   = (const float*)d_in[3];
  const float* ab   = (const float*)d_in[4];
  const float* pw   = (const float*)d_in[5];
  const float* pb   = (const float*)d_in[6];
  const float* fw   = (const float*)d_in[7];
  const float* fb   = (const float*)d_in[8];
  const float* f2w  = (const float*)d_in[9];
  const float* f2bi = (const float*)d_in[10];
  const float* l1w  = (const float*)d_in[11];
  const float* l1b  = (const float*)d_in[12];
  const float* l2w  = (const float*)d_in[13];
  const float* l2b  = (const float*)d_in[14];
  const float* lnfw = (const float*)d_in[15];
  const float* lnfb = (const float*)d_in[16];

  char* ws = (char*)d_ws;
  size_t off = 0;
  auto take = [&](size_t bytes) -> void* {
    void* p = ws + off;
    off += (bytes + 255) & ~(size_t)255;
    return p;
  };
  ushort* wte_b = (ushort*)take((size_t)VV * DDIM * 2);
  ushort* aw_b  = (ushort*)take((size_t)LL * 3 * DDIM * DDIM * 2);
  ushort* pw_b  = (ushort*)take((size_t)LL * DDIM * DDIM * 2);
  ushort* fw_b  = (ushort*)take((size_t)LL * FF * DDIM * 2);
  ushort* f2w_b = (ushort*)take((size_t)LL * DDIM * FF * 2);
  float*  x     = (float*)take((size_t)MM * DDIM * 4);
  ushort* xb    = (ushort*)take((size_t)MM * DDIM * 2);
  ushort* qkv_b = (ushort*)take((size_t)MM * 3 * DDIM * 2);
  ushort* yb    = (ushort*)take((size_t)MM * DDIM * 2);
  ushort* tmp_b = (ushort*)take((size_t)2 * MM * DDIM * 2);  // 2 bf16 split-K planes
  ushort* hb    = (ushort*)take((size_t)MM * FF * 2);

  cvt_all<<<dim3((unsigned)(CW4 / 4 / 256)), dim3(256), 0, stream>>>(
      wte, aw, pw, fw, f2w, wte_b);

  embed_kernel<<<dim3(MM), dim3(128), 0, stream>>>(idx, wte, wpe, x, xb);

  for (int l = 0; l < LL; ++l) {
    gemm_bt64<0, 1, 128, 64, 1><<<dim3(24, 24), dim3(256), 0, stream>>>(
        xb, aw_b + (size_t)l * 3 * DDIM * DDIM, ab + (size_t)l * 3 * DDIM, qkv_b, 3 * DDIM, DDIM);
    attn_mfma<<<dim3(TT / 64, BB * 8), dim3(256), 0, stream>>>(qkv_b, yb);
    gemm_bt64<0, 1, 64, 64, 2><<<dim3(8, 48, 2), dim3(256), 0, stream>>>(
        yb, pw_b + (size_t)l * DDIM * DDIM, pb + (size_t)l * DDIM, tmp_b, DDIM, DDIM);
    add_ln<2><<<dim3(MM / 4), dim3(256), 0, stream>>>(
        x, tmp_b, l1w + (size_t)l * DDIM, l1b + (size_t)l * DDIM, x, xb);
    gemm_bt64<1, 1, 128, 64, 1><<<dim3(32, 24), dim3(256), 0, stream>>>(
        xb, fw_b + (size_t)l * FF * DDIM, fb + (size_t)l * FF, hb, FF, DDIM);
    gemm_bt64<0, 1, 64, 64, 2><<<dim3(8, 48, 2), dim3(256), 0, stream>>>(
        hb, f2w_b + (size_t)l * DDIM * FF, f2bi + (size_t)l * DDIM, tmp_b, DDIM, FF);
    add_ln<2><<<dim3(MM / 4), dim3(256), 0, stream>>>(
        x, tmp_b, l2w + (size_t)l * DDIM, l2b + (size_t)l * DDIM, x, xb);
  }
  add_ln<0><<<dim3(MM / 4), dim3(256), 0, stream>>>(x, nullptr, lnfw, lnfb, x, xb);

  gemm_head<<<dim3((VV / 128) * 24), dim3(256), 0, stream>>>(
      xb, wte_b, (float*)d_out, VV, DDIM);
}